// Round 5
// baseline (585.402 us; speedup 1.0000x reference)
//
#include <hip/hip_runtime.h>
#include <math.h>

// GAT 3-layer, MI355X. Round 11:
// - k_attn inner loop reverted to R8 (best: 570us total). R9/R10 pipeline
//   attempts were neutral-negative; gather is fabric-BW-bound at ~3.7 TB/s.
// - Each k_attn split into TWO half-range dispatches (dbase/nmax): same work,
//   drops attn below mid-tier kernels in the top-5 profile so fuse1/gemm/
//   part/csr durations become visible next round.

#define LRELU(x) ((x) > 0.f ? (x) : 0.2f*(x))
#define SH 8          // bucket = dst >> 8 (256 nodes per bucket)
#define TILE 4096
#define EPT 16

typedef __attribute__((ext_vector_type(8))) short s16x8;
typedef __attribute__((ext_vector_type(4))) float f32x4;

__device__ inline unsigned short f2bf(float f){
  unsigned u = __float_as_uint(f);
  u += 0x7fff + ((u >> 16) & 1);   // round-to-nearest-even
  return (unsigned short)(u >> 16);
}

// ---------------- init: zero bcnt + psum ----------------
__global__ void k_init(int* __restrict__ bcnt, float* __restrict__ psum){
  int t = threadIdx.x;
  bcnt[t] = 0; bcnt[256 + t] = 0;
  for (int i = t; i < 8192; i += 256) psum[i] = 0.f;
}

// ---------------- MFMA bf16 GEMM body (shared by k_gemm / k_fuse1) -------
// Block 256 (4 waves). Tile 64 rows x 128 cols, K=128. Wave w owns cols
// [32w, 32w+32). W^T staged once per block in LDS (bf16, XOR-swizzled).
// Accumulators round-trip through Xl -> coalesced xw store + local al/ar dot.
template<bool BF16IN>
__device__ __forceinline__ void gemm_body(
    unsigned short* Wt, unsigned short* Xl,
    const void* __restrict__ Xv, const float* __restrict__ W,
    const float* __restrict__ attl, const float* __restrict__ attr,
    unsigned short* __restrict__ XW, float* __restrict__ AL, float* __restrict__ AR,
    int n, int bid, int gstride)
{
  int t = threadIdx.x;
  int lane = t & 63, w = t >> 6;
  int l15 = lane & 15, quad = lane >> 4;
  // stage W^T bf16, chunk-swizzled: Wt[n][ ((k/8 ^ (n&15))*8 + k%8 ]
  for (int i = 0; i < 64; i++){
    int e = i*256 + t;
    int k = e >> 7, nn = e & 127;
    Wt[nn*128 + ((((k>>3) ^ (nn&15))<<3) | (k&7))] = f2bf(W[e]);
  }
  int ntiles = (n + 63) >> 6;
  int r_ = t >> 2, seg = t & 3;
  for (int tile = bid; tile < ntiles; tile += gstride){
    int row0 = tile << 6;
    __syncthreads();
    {  // stage X tile as bf16
      int grow = row0 + r_;
      unsigned short* dp = &Xl[r_*136 + seg*32];
      if (grow < n){
        if (BF16IN){
          const uint4* gp = (const uint4*)((const unsigned short*)Xv + (size_t)grow*128 + seg*32);
          #pragma unroll
          for (int i = 0; i < 4; i++) ((uint4*)dp)[i] = gp[i];
        } else {
          const float4* gp = (const float4*)((const float*)Xv + (size_t)grow*128 + seg*32);
          #pragma unroll
          for (int i = 0; i < 8; i++){
            float4 v = gp[i];
            ((unsigned*)dp)[i*2]   = (unsigned)f2bf(v.x) | ((unsigned)f2bf(v.y) << 16);
            ((unsigned*)dp)[i*2+1] = (unsigned)f2bf(v.z) | ((unsigned)f2bf(v.w) << 16);
          }
        }
      } else {
        #pragma unroll
        for (int i = 0; i < 4; i++) ((uint4*)dp)[i] = make_uint4(0,0,0,0);
      }
    }
    __syncthreads();
    f32x4 acc[4][2];
    #pragma unroll
    for (int rt = 0; rt < 4; rt++){ acc[rt][0] = (f32x4){0,0,0,0}; acc[rt][1] = (f32x4){0,0,0,0}; }
    #pragma unroll
    for (int ks = 0; ks < 4; ks++){
      s16x8 b0 = *(const s16x8*)&Wt[(w*32 + l15)*128      + (((ks*4+quad) ^ l15)<<3)];
      s16x8 b1 = *(const s16x8*)&Wt[(w*32 + 16 + l15)*128 + (((ks*4+quad) ^ l15)<<3)];
      #pragma unroll
      for (int rt = 0; rt < 4; rt++){
        s16x8 a = *(const s16x8*)&Xl[(rt*16 + l15)*136 + ks*32 + quad*8];
        acc[rt][0] = __builtin_amdgcn_mfma_f32_16x16x32_bf16(a, b0, acc[rt][0], 0, 0, 0);
        acc[rt][1] = __builtin_amdgcn_mfma_f32_16x16x32_bf16(a, b1, acc[rt][1], 0, 0, 0);
      }
    }
    __syncthreads();
    // C layout: col = l15, row = quad*4 + reg
    #pragma unroll
    for (int rt = 0; rt < 4; rt++)
      #pragma unroll
      for (int c2 = 0; c2 < 2; c2++)
        #pragma unroll
        for (int r = 0; r < 4; r++)
          Xl[(rt*16 + quad*4 + r)*136 + w*32 + c2*16 + l15] = f2bf(acc[rt][c2][r]);
    __syncthreads();
    {  // epilogue: thread -> (row r_, head seg)
      int grow = row0 + r_;
      if (grow < n){
        const unsigned short* sp = &Xl[r_*136 + seg*32];
        uint4 uu[4];
        #pragma unroll
        for (int i = 0; i < 4; i++) uu[i] = ((const uint4*)sp)[i];
        unsigned short* gx = XW + (size_t)grow*128 + seg*32;
        #pragma unroll
        for (int i = 0; i < 4; i++) ((uint4*)gx)[i] = uu[i];
        const unsigned* up = (const unsigned*)uu;
        const float4* alp = (const float4*)(attl + seg*32);
        const float4* arp = (const float4*)(attr + seg*32);
        float pl = 0.f, pr = 0.f;
        #pragma unroll
        for (int i = 0; i < 8; i++){
          unsigned ua = up[i*2], ub = up[i*2+1];
          float x0 = __uint_as_float(ua << 16);
          float x1 = __uint_as_float(ua & 0xffff0000u);
          float x2 = __uint_as_float(ub << 16);
          float x3 = __uint_as_float(ub & 0xffff0000u);
          float4 av = alp[i];
          float4 rv = arp[i];
          pl += x0*av.x + x1*av.y + x2*av.z + x3*av.w;
          pr += x0*rv.x + x1*rv.y + x2*rv.z + x3*rv.w;
        }
        AL[grow*4 + seg] = pl;
        AR[grow*4 + seg] = pr;
      }
    }
  }
}

template<bool BF16IN>
__global__ __launch_bounds__(256) void k_gemm(
    const void* __restrict__ Xv, const float* __restrict__ W,
    const float* __restrict__ attl, const float* __restrict__ attr,
    unsigned short* __restrict__ XW, float* __restrict__ AL, float* __restrict__ AR, int n)
{
  __shared__ unsigned short Wt[128*128];
  __shared__ unsigned short Xl[64*136];
  gemm_body<BF16IN>(Wt, Xl, Xv, W, attl, attr, XW, AL, AR, n, blockIdx.x, gridDim.x);
}

// ---------------- fused: bucket histogram (blocks < nparts) + GEMM-1 ----
__global__ __launch_bounds__(256) void k_fuse1(
    const int* __restrict__ dst, int* __restrict__ bcnt, int E, int nparts,
    const float* __restrict__ X, const float* __restrict__ W,
    const float* __restrict__ attl, const float* __restrict__ attr,
    unsigned short* __restrict__ XW, float* __restrict__ AL, float* __restrict__ AR, int n)
{
  __shared__ unsigned short Wt[128*128];
  __shared__ unsigned short Xl[64*136];
  if ((int)blockIdx.x < nparts){
    int* lh = (int*)Wt;     // alias histogram onto Wt
    int t = threadIdx.x;
    for (int j = t; j < 512; j += 256) lh[j] = 0;
    __syncthreads();
    int base = blockIdx.x * TILE;
    int lim = min(base + TILE, E);
    for (int e = base + t; e < lim; e += 256)
      atomicAdd(&lh[dst[e] >> SH], 1);
    __syncthreads();
    for (int j = t; j < 512; j += 256){
      int v = lh[j];
      if (v) atomicAdd(&bcnt[j], v);
    }
    return;
  }
  gemm_body<false>(Wt, Xl, X, W, attl, attr, XW, AL, AR, n,
                   (int)blockIdx.x - nparts, (int)gridDim.x - nparts);
}

// ---------------- bucket scan (block 0) + graph bounds (block 1) --------
__global__ __launch_bounds__(256) void k_bscan(const int* __restrict__ bcnt,
    int* __restrict__ bstart, int* __restrict__ bfill, int NB, int E,
    const int* __restrict__ batch, int* __restrict__ gstart, int n){
  int t = threadIdx.x;
  if (blockIdx.x == 1){
    int g = t;
    if (g > 64) return;
    int lo = 0, hi = n;
    while (lo < hi){
      int mid = (lo + hi) >> 1;
      if (batch[mid] < g) lo = mid + 1; else hi = mid;
    }
    gstart[g] = lo;
    return;
  }
  __shared__ int c[512];
  __shared__ int ps[256];
  for (int j = t; j < 512; j += 256) c[j] = (j < NB) ? bcnt[j] : 0;
  __syncthreads();
  int b0 = 2*t;
  int v0 = c[b0], v1 = c[b0+1];
  int ts = v0 + v1;
  ps[t] = ts; __syncthreads();
  for (int off = 1; off < 256; off <<= 1){
    int x = (t >= off) ? ps[t-off] : 0; __syncthreads();
    ps[t] += x; __syncthreads();
  }
  int pre = ps[t] - ts;
  if (b0   < NB){ bstart[b0]   = pre;    bfill[b0]   = pre; }
  if (b0+1 < NB){ bstart[b0+1] = pre+v0; bfill[b0+1] = pre+v0; }
  if (t == 0) bstart[NB] = E;
}

// LDS multi-split: tile of 4096 edges ranked by bucket, flushed as
// bucket-contiguous runs (~10-edge bursts at SH=8).
__global__ __launch_bounds__(256) void k_part(const int* __restrict__ src,
    const int* __restrict__ dst, int* __restrict__ bfill,
    int2* __restrict__ tmp, int E){
  __shared__ int2 reorder[TILE];
  __shared__ int lhist[512], lscan[512], lgbase[512];
  __shared__ int ps[256];
  int t = threadIdx.x;
  int tb = blockIdx.x * TILE;
  int tilecnt = min(TILE, E - tb);
  for (int j = t; j < 512; j += 256) lhist[j] = 0;
  __syncthreads();
  int ss[EPT], dd[EPT], rk[EPT];
  #pragma unroll
  for (int i = 0; i < EPT; i++){
    int e = tb + t + i*256;
    if (e < E){
      ss[i] = src[e]; dd[i] = dst[e];
      rk[i] = atomicAdd(&lhist[dd[i] >> SH], 1);
    }
  }
  __syncthreads();
  int b0 = 2*t;
  int v0 = lhist[b0], v1 = lhist[b0+1];
  int ts = v0 + v1;
  ps[t] = ts; __syncthreads();
  for (int off = 1; off < 256; off <<= 1){
    int x = (t >= off) ? ps[t-off] : 0; __syncthreads();
    ps[t] += x; __syncthreads();
  }
  int pre = ps[t] - ts;
  int ex0 = pre, ex1 = pre + v0;
  lscan[b0] = ex0; lscan[b0+1] = ex1;
  if (v0 > 0){ int gb = atomicAdd(&bfill[b0],   v0); lgbase[b0]   = gb - ex0; }
  if (v1 > 0){ int gb = atomicAdd(&bfill[b0+1], v1); lgbase[b0+1] = gb - ex1; }
  __syncthreads();
  #pragma unroll
  for (int i = 0; i < EPT; i++){
    int e = tb + t + i*256;
    if (e < E){
      int b = dd[i] >> SH;
      reorder[lscan[b] + rk[i]] = make_int2(ss[i], dd[i]);
    }
  }
  __syncthreads();
  for (int j = t; j < tilecnt; j += 256){
    int2 p = reorder[j];
    tmp[lgbase[p.y >> SH] + j] = p;
  }
}

// One block per bucket (256 nodes): per-node offsets via LDS scan (-> rp),
// then scatter src into the bucket's ~16KB col window (single-CU, merges).
__global__ __launch_bounds__(256) void k_csr(const int2* __restrict__ tmp,
    const int* __restrict__ bstart, int* __restrict__ rp, int* __restrict__ col,
    int n, int E){
  __shared__ int lcnt[256];
  __shared__ int sc[256];
  int b = blockIdx.x, t = threadIdx.x;
  int node0 = b << SH;
  int ncnt = min(256, n - node0);
  int be = bstart[b], ee = bstart[b+1];
  lcnt[t] = 0;
  __syncthreads();
  for (int e = be + t; e < ee; e += 256)
    atomicAdd(&lcnt[tmp[e].y - node0], 1);
  __syncthreads();
  int v = lcnt[t];
  sc[t] = v;
  __syncthreads();
  for (int off = 1; off < 256; off <<= 1){
    int x = (t >= off) ? sc[t-off] : 0;
    __syncthreads();
    sc[t] += x;
    __syncthreads();
  }
  int start = be + sc[t] - v;     // exclusive
  lcnt[t] = start;
  if (t < ncnt) rp[node0 + t] = start;
  if (t == 0 && node0 + ncnt == n) rp[n] = E;
  __syncthreads();
  for (int e = be + t; e < ee; e += 256){
    int2 p = tmp[e];
    int pos = atomicAdd(&lcnt[p.y - node0], 1);
    col[pos] = p.x;
  }
}

// ---------------- Attention + aggregate: 4 dsts per wave ----------------
// 16-lane group g owns dst dbase+...+g; lane r owns channels 8r..8r+7.
// Phase 1 (wave-wide): weights for the union edge range packed into LDS as
// int2 {src<<4, w_h}. Phase 2 (per group): per-lane accumulation, no
// cross-lane reductions. Range-split via (dbase, nmax) for profiling split.
template<bool BF16OUT>
__global__ __launch_bounds__(256) void k_attn(
    const unsigned short* __restrict__ XW, const float* __restrict__ AL, const float* __restrict__ AR,
    const int* __restrict__ rp, const int* __restrict__ col,
    const float* __restrict__ bias, void* __restrict__ OUT, int dbase, int nmax)
{
  __shared__ int   ws[4][512];       // per wave: 64 edges x 4 heads x {s<<4, w}
  __shared__ float arsh[4][4][4];    // per wave: 4 dsts' ar (4 heads)
  int wv = threadIdx.x >> 6;
  int lane = threadIdx.x & 63;
  int r = lane & 15, g = lane >> 4, h2 = r >> 2;
  int d0 = dbase + (blockIdx.x*4 + wv)*4;
  if (d0 >= nmax) return;
  int d = d0 + g;
  bool valid = d < nmax;
  int dc = valid ? d : nmax-1;
  int rs = rp[dc];
  int re = valid ? rp[dc+1] : rs;
  float4 ard4 = ((const float4*)AR)[dc];
  if (r == 0) *(float4*)&arsh[wv][g][0] = ard4;
  float4 ald4 = ((const float4*)AL)[dc];
  float alh = h2==0?ald4.x : h2==1?ald4.y : h2==2?ald4.z : ald4.w;
  float arh = h2==0?ard4.x : h2==1?ard4.y : h2==2?ard4.z : ard4.w;
  float tse = alh + arh;
  float eself = __expf(fmaxf(tse, 0.2f*tse));
  const uint4* XW4 = (const uint4*)XW;
  float acc[8];
  {  // self term
    uint4 v = XW4[(size_t)dc*16 + r];
    acc[0] = eself * __uint_as_float(v.x << 16);
    acc[1] = eself * __uint_as_float(v.x & 0xffff0000u);
    acc[2] = eself * __uint_as_float(v.y << 16);
    acc[3] = eself * __uint_as_float(v.y & 0xffff0000u);
    acc[4] = eself * __uint_as_float(v.z << 16);
    acc[5] = eself * __uint_as_float(v.z & 0xffff0000u);
    acc[6] = eself * __uint_as_float(v.w << 16);
    acc[7] = eself * __uint_as_float(v.w & 0xffff0000u);
  }
  int ub0 = rp[d0];
  int ubE = rp[min(d0+4, nmax)];
  int reb = valid ? re : 0x7fffffff;
  int b1 = __shfl(reb, 0, 64);
  int b2 = __shfl(reb, 16, 64);
  int b3 = __shfl(reb, 32, 64);
  int* wsw = ws[wv];
  float zacc = eself;
  for (int cb = ub0; cb < ubE; cb += 64){
    int cnt = min(64, ubE - cb);
    if (lane < cnt){
      int e = cb + lane;
      int s = col[e];
      int eg = (e >= b1) + (e >= b2) + (e >= b3);
      float4 arr = *(const float4*)&arsh[wv][eg][0];
      float4 a = ((const float4*)AL)[s];
      float t0 = a.x + arr.x, t1 = a.y + arr.y, t2 = a.z + arr.z, t3 = a.w + arr.w;
      float w0 = __expf(fmaxf(t0, 0.2f*t0));
      float w1 = __expf(fmaxf(t1, 0.2f*t1));
      float w2 = __expf(fmaxf(t2, 0.2f*t2));
      float w3 = __expf(fmaxf(t3, 0.2f*t3));
      int s4 = s << 4;
      ((int4*)&wsw[lane*8])[0] = make_int4(s4, __float_as_int(w0), s4, __float_as_int(w1));
      ((int4*)&wsw[lane*8])[1] = make_int4(s4, __float_as_int(w2), s4, __float_as_int(w3));
    }
    int jlo = max(rs - cb, 0);
    int jhi = min(re - cb, cnt);
    #pragma unroll 4
    for (int j = jlo; j < jhi; ++j){
      int2 q = *(const int2*)&wsw[j*8 + h2*2];
      float w = __int_as_float(q.y);
      uint4 u = XW4[(unsigned)(q.x + r)];
      acc[0] = fmaf(w, __uint_as_float(u.x << 16), acc[0]);
      acc[1] = fmaf(w, __uint_as_float(u.x & 0xffff0000u), acc[1]);
      acc[2] = fmaf(w, __uint_as_float(u.y << 16), acc[2]);
      acc[3] = fmaf(w, __uint_as_float(u.y & 0xffff0000u), acc[3]);
      acc[4] = fmaf(w, __uint_as_float(u.z << 16), acc[4]);
      acc[5] = fmaf(w, __uint_as_float(u.z & 0xffff0000u), acc[5]);
      acc[6] = fmaf(w, __uint_as_float(u.w << 16), acc[6]);
      acc[7] = fmaf(w, __uint_as_float(u.w & 0xffff0000u), acc[7]);
      zacc += w;
    }
  }
  float rz = 1.f / zacc;
  float4 bb0 = ((const float4*)bias)[r*2];
  float4 bb1 = ((const float4*)bias)[r*2 + 1];
  float o[8];
  o[0] = fmaf(acc[0], rz, bb0.x); o[1] = fmaf(acc[1], rz, bb0.y);
  o[2] = fmaf(acc[2], rz, bb0.z); o[3] = fmaf(acc[3], rz, bb0.w);
  o[4] = fmaf(acc[4], rz, bb1.x); o[5] = fmaf(acc[5], rz, bb1.y);
  o[6] = fmaf(acc[6], rz, bb1.z); o[7] = fmaf(acc[7], rz, bb1.w);
  #pragma unroll
  for (int i = 0; i < 8; i++) o[i] = o[i] > 0.f ? o[i] : 0.f;
  if (valid){
    if (BF16OUT){
      uint4 pk;
      pk.x = (unsigned)f2bf(o[0]) | ((unsigned)f2bf(o[1]) << 16);
      pk.y = (unsigned)f2bf(o[2]) | ((unsigned)f2bf(o[3]) << 16);
      pk.z = (unsigned)f2bf(o[4]) | ((unsigned)f2bf(o[5]) << 16);
      pk.w = (unsigned)f2bf(o[6]) | ((unsigned)f2bf(o[7]) << 16);
      ((uint4*)OUT)[(size_t)d*16 + r] = pk;
    } else {
      float4 f0; f0.x = o[0]; f0.y = o[1]; f0.z = o[2]; f0.w = o[3];
      float4 f1; f1.x = o[4]; f1.y = o[5]; f1.z = o[6]; f1.w = o[7];
      ((float4*)OUT)[(size_t)d*32 + r*2]     = f0;
      ((float4*)OUT)[(size_t)d*32 + r*2 + 1] = f1;
    }
  }
}

// ---------------- pooling + MLP head ----------------
__global__ __launch_bounds__(128) void k_pool(const float* __restrict__ H,
                                              const int* __restrict__ gstart,
                                              float* __restrict__ psum){
  int g = blockIdx.x >> 3, slice = blockIdx.x & 7, t = threadIdx.x;
  int s0 = gstart[g], s1 = gstart[g+1];
  int cntg = s1 - s0;
  int chunk = (cntg + 7) >> 3;
  int lo = s0 + slice*chunk;
  int hi = min(lo + chunk, s1);
  float sum = 0.f;
  for (int i = lo; i < hi; i++) sum += H[(size_t)i*128 + t];
  atomicAdd(&psum[g*128 + t], sum);
}

__global__ __launch_bounds__(128) void k_mlp(const float* __restrict__ psum,
                       const int* __restrict__ gstart,
                       const float* __restrict__ w1, const float* __restrict__ b1,
                       const float* __restrict__ w2, const float* __restrict__ b2,
                       float* __restrict__ out)
{
  __shared__ float p[128];
  __shared__ float gsh[128];
  __shared__ float lg[10];
  int g = blockIdx.x, t = threadIdx.x;
  float c = fmaxf((float)(gstart[g+1] - gstart[g]), 1.f);
  p[t] = psum[g*128 + t] / c;
  __syncthreads();
  float acc = b1[t];
  for (int k = 0; k < 128; k++) acc = fmaf(p[k], w1[k*128 + t], acc);
  gsh[t] = acc > 0.f ? acc : 0.f;
  __syncthreads();
  if (t < 10){
    float a = b2[t];
    for (int k = 0; k < 128; k++) a = fmaf(gsh[k], w2[k*10 + t], a);
    lg[t] = a;
  }
  __syncthreads();
  if (t < 10){
    float mx = lg[0];
    for (int c2 = 1; c2 < 10; c2++) mx = fmaxf(mx, lg[c2]);
    float se = 0.f;
    for (int c2 = 0; c2 < 10; c2++) se += __expf(lg[c2] - mx);
    out[g*10 + t] = lg[t] - mx - logf(se);
  }
}

extern "C" void kernel_launch(void* const* d_in, const int* in_sizes, int n_in,
                              void* d_out, int out_size, void* d_ws, size_t ws_size,
                              hipStream_t stream)
{
  const float* x    = (const float*)d_in[0];
  const int* eidx   = (const int*)d_in[1];
  const int* batch  = (const int*)d_in[2];
  const float* W[3]  = {(const float*)d_in[3], (const float*)d_in[7],  (const float*)d_in[11]};
  const float* al[3] = {(const float*)d_in[4], (const float*)d_in[8],  (const float*)d_in[12]};
  const float* ar[3] = {(const float*)d_in[5], (const float*)d_in[9],  (const float*)d_in[13]};
  const float* bs[3] = {(const float*)d_in[6], (const float*)d_in[10], (const float*)d_in[14]};
  const float* l1w = (const float*)d_in[15];
  const float* l1b = (const float*)d_in[16];
  const float* l2w = (const float*)d_in[17];
  const float* l2b = (const float*)d_in[18];
  int E = in_sizes[1] / 2;
  int n = in_sizes[2];            // 100000
  const int* srcp = eidx;
  const int* dstp = eidx + E;
  int NB = (n + 255) >> SH;       // 391 buckets (<=512)

  char* wsp = (char*)d_ws;
  auto alloc = [&](size_t bytes){ void* p = (void*)wsp; wsp += (bytes + 255) & ~(size_t)255; return p; };
  unsigned short* xw   = (unsigned short*)alloc((size_t)n*128*2);  // 25.6 MB bf16
  unsigned short* hbuf = (unsigned short*)alloc((size_t)n*128*2);  // 25.6 MB bf16
  float* ALb  = (float*)alloc((size_t)n*4*4);
  float* ARb  = (float*)alloc((size_t)n*4*4);
  int* rp     = (int*)alloc((size_t)(n+1)*4);
  int* col    = (int*)alloc((size_t)E*4);          // 6.4 MB
  int2* tmp   = (int2*)alloc((size_t)E*8);         // 12.8 MB bucketed pairs
  int* bcnt   = (int*)alloc(512*4);
  int* bstart = (int*)alloc(513*4);
  int* bfill  = (int*)alloc(512*4);
  float* psum = (float*)alloc(64*128*4);
  int* gstart = (int*)alloc(65*4);

  float* outlog = (float*)d_out;
  float* h3     = (float*)d_out + 64*10;

  int nparts = (E + TILE - 1) / TILE;   // 391

  k_init<<<1, 256, 0, stream>>>(bcnt, psum);
  // fused: bucket histogram + layer-1 GEMM (independent, co-resident)
  k_fuse1<<<nparts + 768, 256, 0, stream>>>(dstp, bcnt, E, nparts,
                                            x, W[0], al[0], ar[0], xw, ALb, ARb, n);
  k_bscan<<<2, 256, 0, stream>>>(bcnt, bstart, bfill, NB, E, batch, gstart, n);
  k_part <<<nparts, 256, 0, stream>>>(srcp, dstp, bfill, tmp, E);
  k_csr  <<<NB, 256, 0, stream>>>(tmp, bstart, rp, col, n, E);

  // attn split into two half-range dispatches (profiling visibility + same work)
  int half = ((n/2) + 15) & ~15;           // group-of-16 aligned
  int ab1 = (half + 15) / 16;
  int ab2 = (n - half + 15) / 16;

  // layer 1 attention (xw ready from fuse1)
  k_attn<true><<<ab1, 256, 0, stream>>>(xw, ALb, ARb, rp, col, bs[0], hbuf, 0, half);
  k_attn<true><<<ab2, 256, 0, stream>>>(xw, ALb, ARb, rp, col, bs[0], hbuf, half, n);
  // layer 2
  k_gemm<true><<<768, 256, 0, stream>>>(hbuf, W[1], al[1], ar[1], xw, ALb, ARb, n);
  k_attn<true><<<ab1, 256, 0, stream>>>(xw, ALb, ARb, rp, col, bs[1], hbuf, 0, half);
  k_attn<true><<<ab2, 256, 0, stream>>>(xw, ALb, ARb, rp, col, bs[1], hbuf, half, n);
  // layer 3 -> fp32 straight into d_out
  k_gemm<true><<<768, 256, 0, stream>>>(hbuf, W[2], al[2], ar[2], xw, ALb, ARb, n);
  k_attn<false><<<ab1, 256, 0, stream>>>(xw, ALb, ARb, rp, col, bs[2], h3, 0, half);
  k_attn<false><<<ab2, 256, 0, stream>>>(xw, ALb, ARb, rp, col, bs[2], h3, half, n);

  k_pool<<<64*8, 128, 0, stream>>>(h3, gstart, psum);
  k_mlp <<<64, 128, 0, stream>>>(psum, gstart, l1w, l1b, l2w, l2b, outlog);
}

// Round 6
// 537.968 us; speedup vs baseline: 1.0882x; 1.0882x over previous
//
#include <hip/hip_runtime.h>
#include <math.h>

// GAT 3-layer, MI355X. Round 12:
// - k_pool fixed: 8 -> 64 slices/graph (512 -> 4096 blocks). R11 profile
//   showed it at 60us, Occupancy 8.8%, VALUBusy 0.9%, 431 GB/s: pure
//   latency-bound under-parallelization. Now ~24 rows/block, BW-bound.
// - attn stays split in halves one more round (mid-tier visibility: any
//   kernel >38us surfaces in next top-5).

#define LRELU(x) ((x) > 0.f ? (x) : 0.2f*(x))
#define SH 8          // bucket = dst >> 8 (256 nodes per bucket)
#define TILE 4096
#define EPT 16
#define PSL 64        // pool slices per graph

typedef __attribute__((ext_vector_type(8))) short s16x8;
typedef __attribute__((ext_vector_type(4))) float f32x4;

__device__ inline unsigned short f2bf(float f){
  unsigned u = __float_as_uint(f);
  u += 0x7fff + ((u >> 16) & 1);   // round-to-nearest-even
  return (unsigned short)(u >> 16);
}

// ---------------- init: zero bcnt + psum ----------------
__global__ void k_init(int* __restrict__ bcnt, float* __restrict__ psum){
  int t = threadIdx.x;
  bcnt[t] = 0; bcnt[256 + t] = 0;
  for (int i = t; i < 8192; i += 256) psum[i] = 0.f;
}

// ---------------- MFMA bf16 GEMM body (shared by k_gemm / k_fuse1) -------
// Block 256 (4 waves). Tile 64 rows x 128 cols, K=128. Wave w owns cols
// [32w, 32w+32). W^T staged once per block in LDS (bf16, XOR-swizzled).
// Accumulators round-trip through Xl -> coalesced xw store + local al/ar dot.
template<bool BF16IN>
__device__ __forceinline__ void gemm_body(
    unsigned short* Wt, unsigned short* Xl,
    const void* __restrict__ Xv, const float* __restrict__ W,
    const float* __restrict__ attl, const float* __restrict__ attr,
    unsigned short* __restrict__ XW, float* __restrict__ AL, float* __restrict__ AR,
    int n, int bid, int gstride)
{
  int t = threadIdx.x;
  int lane = t & 63, w = t >> 6;
  int l15 = lane & 15, quad = lane >> 4;
  // stage W^T bf16, chunk-swizzled: Wt[n][ ((k/8 ^ (n&15))*8 + k%8 ]
  for (int i = 0; i < 64; i++){
    int e = i*256 + t;
    int k = e >> 7, nn = e & 127;
    Wt[nn*128 + ((((k>>3) ^ (nn&15))<<3) | (k&7))] = f2bf(W[e]);
  }
  int ntiles = (n + 63) >> 6;
  int r_ = t >> 2, seg = t & 3;
  for (int tile = bid; tile < ntiles; tile += gstride){
    int row0 = tile << 6;
    __syncthreads();
    {  // stage X tile as bf16
      int grow = row0 + r_;
      unsigned short* dp = &Xl[r_*136 + seg*32];
      if (grow < n){
        if (BF16IN){
          const uint4* gp = (const uint4*)((const unsigned short*)Xv + (size_t)grow*128 + seg*32);
          #pragma unroll
          for (int i = 0; i < 4; i++) ((uint4*)dp)[i] = gp[i];
        } else {
          const float4* gp = (const float4*)((const float*)Xv + (size_t)grow*128 + seg*32);
          #pragma unroll
          for (int i = 0; i < 8; i++){
            float4 v = gp[i];
            ((unsigned*)dp)[i*2]   = (unsigned)f2bf(v.x) | ((unsigned)f2bf(v.y) << 16);
            ((unsigned*)dp)[i*2+1] = (unsigned)f2bf(v.z) | ((unsigned)f2bf(v.w) << 16);
          }
        }
      } else {
        #pragma unroll
        for (int i = 0; i < 4; i++) ((uint4*)dp)[i] = make_uint4(0,0,0,0);
      }
    }
    __syncthreads();
    f32x4 acc[4][2];
    #pragma unroll
    for (int rt = 0; rt < 4; rt++){ acc[rt][0] = (f32x4){0,0,0,0}; acc[rt][1] = (f32x4){0,0,0,0}; }
    #pragma unroll
    for (int ks = 0; ks < 4; ks++){
      s16x8 b0 = *(const s16x8*)&Wt[(w*32 + l15)*128      + (((ks*4+quad) ^ l15)<<3)];
      s16x8 b1 = *(const s16x8*)&Wt[(w*32 + 16 + l15)*128 + (((ks*4+quad) ^ l15)<<3)];
      #pragma unroll
      for (int rt = 0; rt < 4; rt++){
        s16x8 a = *(const s16x8*)&Xl[(rt*16 + l15)*136 + ks*32 + quad*8];
        acc[rt][0] = __builtin_amdgcn_mfma_f32_16x16x32_bf16(a, b0, acc[rt][0], 0, 0, 0);
        acc[rt][1] = __builtin_amdgcn_mfma_f32_16x16x32_bf16(a, b1, acc[rt][1], 0, 0, 0);
      }
    }
    __syncthreads();
    // C layout: col = l15, row = quad*4 + reg
    #pragma unroll
    for (int rt = 0; rt < 4; rt++)
      #pragma unroll
      for (int c2 = 0; c2 < 2; c2++)
        #pragma unroll
        for (int r = 0; r < 4; r++)
          Xl[(rt*16 + quad*4 + r)*136 + w*32 + c2*16 + l15] = f2bf(acc[rt][c2][r]);
    __syncthreads();
    {  // epilogue: thread -> (row r_, head seg)
      int grow = row0 + r_;
      if (grow < n){
        const unsigned short* sp = &Xl[r_*136 + seg*32];
        uint4 uu[4];
        #pragma unroll
        for (int i = 0; i < 4; i++) uu[i] = ((const uint4*)sp)[i];
        unsigned short* gx = XW + (size_t)grow*128 + seg*32;
        #pragma unroll
        for (int i = 0; i < 4; i++) ((uint4*)gx)[i] = uu[i];
        const unsigned* up = (const unsigned*)uu;
        const float4* alp = (const float4*)(attl + seg*32);
        const float4* arp = (const float4*)(attr + seg*32);
        float pl = 0.f, pr = 0.f;
        #pragma unroll
        for (int i = 0; i < 8; i++){
          unsigned ua = up[i*2], ub = up[i*2+1];
          float x0 = __uint_as_float(ua << 16);
          float x1 = __uint_as_float(ua & 0xffff0000u);
          float x2 = __uint_as_float(ub << 16);
          float x3 = __uint_as_float(ub & 0xffff0000u);
          float4 av = alp[i];
          float4 rv = arp[i];
          pl += x0*av.x + x1*av.y + x2*av.z + x3*av.w;
          pr += x0*rv.x + x1*rv.y + x2*rv.z + x3*rv.w;
        }
        AL[grow*4 + seg] = pl;
        AR[grow*4 + seg] = pr;
      }
    }
  }
}

template<bool BF16IN>
__global__ __launch_bounds__(256) void k_gemm(
    const void* __restrict__ Xv, const float* __restrict__ W,
    const float* __restrict__ attl, const float* __restrict__ attr,
    unsigned short* __restrict__ XW, float* __restrict__ AL, float* __restrict__ AR, int n)
{
  __shared__ unsigned short Wt[128*128];
  __shared__ unsigned short Xl[64*136];
  gemm_body<BF16IN>(Wt, Xl, Xv, W, attl, attr, XW, AL, AR, n, blockIdx.x, gridDim.x);
}

// ---------------- fused: bucket histogram (blocks < nparts) + GEMM-1 ----
__global__ __launch_bounds__(256) void k_fuse1(
    const int* __restrict__ dst, int* __restrict__ bcnt, int E, int nparts,
    const float* __restrict__ X, const float* __restrict__ W,
    const float* __restrict__ attl, const float* __restrict__ attr,
    unsigned short* __restrict__ XW, float* __restrict__ AL, float* __restrict__ AR, int n)
{
  __shared__ unsigned short Wt[128*128];
  __shared__ unsigned short Xl[64*136];
  if ((int)blockIdx.x < nparts){
    int* lh = (int*)Wt;     // alias histogram onto Wt
    int t = threadIdx.x;
    for (int j = t; j < 512; j += 256) lh[j] = 0;
    __syncthreads();
    int base = blockIdx.x * TILE;
    int lim = min(base + TILE, E);
    for (int e = base + t; e < lim; e += 256)
      atomicAdd(&lh[dst[e] >> SH], 1);
    __syncthreads();
    for (int j = t; j < 512; j += 256){
      int v = lh[j];
      if (v) atomicAdd(&bcnt[j], v);
    }
    return;
  }
  gemm_body<false>(Wt, Xl, X, W, attl, attr, XW, AL, AR, n,
                   (int)blockIdx.x - nparts, (int)gridDim.x - nparts);
}

// ---------------- bucket scan (block 0) + graph bounds (block 1) --------
__global__ __launch_bounds__(256) void k_bscan(const int* __restrict__ bcnt,
    int* __restrict__ bstart, int* __restrict__ bfill, int NB, int E,
    const int* __restrict__ batch, int* __restrict__ gstart, int n){
  int t = threadIdx.x;
  if (blockIdx.x == 1){
    int g = t;
    if (g > 64) return;
    int lo = 0, hi = n;
    while (lo < hi){
      int mid = (lo + hi) >> 1;
      if (batch[mid] < g) lo = mid + 1; else hi = mid;
    }
    gstart[g] = lo;
    return;
  }
  __shared__ int c[512];
  __shared__ int ps[256];
  for (int j = t; j < 512; j += 256) c[j] = (j < NB) ? bcnt[j] : 0;
  __syncthreads();
  int b0 = 2*t;
  int v0 = c[b0], v1 = c[b0+1];
  int ts = v0 + v1;
  ps[t] = ts; __syncthreads();
  for (int off = 1; off < 256; off <<= 1){
    int x = (t >= off) ? ps[t-off] : 0; __syncthreads();
    ps[t] += x; __syncthreads();
  }
  int pre = ps[t] - ts;
  if (b0   < NB){ bstart[b0]   = pre;    bfill[b0]   = pre; }
  if (b0+1 < NB){ bstart[b0+1] = pre+v0; bfill[b0+1] = pre+v0; }
  if (t == 0) bstart[NB] = E;
}

// LDS multi-split: tile of 4096 edges ranked by bucket, flushed as
// bucket-contiguous runs (~10-edge bursts at SH=8).
__global__ __launch_bounds__(256) void k_part(const int* __restrict__ src,
    const int* __restrict__ dst, int* __restrict__ bfill,
    int2* __restrict__ tmp, int E){
  __shared__ int2 reorder[TILE];
  __shared__ int lhist[512], lscan[512], lgbase[512];
  __shared__ int ps[256];
  int t = threadIdx.x;
  int tb = blockIdx.x * TILE;
  int tilecnt = min(TILE, E - tb);
  for (int j = t; j < 512; j += 256) lhist[j] = 0;
  __syncthreads();
  int ss[EPT], dd[EPT], rk[EPT];
  #pragma unroll
  for (int i = 0; i < EPT; i++){
    int e = tb + t + i*256;
    if (e < E){
      ss[i] = src[e]; dd[i] = dst[e];
      rk[i] = atomicAdd(&lhist[dd[i] >> SH], 1);
    }
  }
  __syncthreads();
  int b0 = 2*t;
  int v0 = lhist[b0], v1 = lhist[b0+1];
  int ts = v0 + v1;
  ps[t] = ts; __syncthreads();
  for (int off = 1; off < 256; off <<= 1){
    int x = (t >= off) ? ps[t-off] : 0; __syncthreads();
    ps[t] += x; __syncthreads();
  }
  int pre = ps[t] - ts;
  int ex0 = pre, ex1 = pre + v0;
  lscan[b0] = ex0; lscan[b0+1] = ex1;
  if (v0 > 0){ int gb = atomicAdd(&bfill[b0],   v0); lgbase[b0]   = gb - ex0; }
  if (v1 > 0){ int gb = atomicAdd(&bfill[b0+1], v1); lgbase[b0+1] = gb - ex1; }
  __syncthreads();
  #pragma unroll
  for (int i = 0; i < EPT; i++){
    int e = tb + t + i*256;
    if (e < E){
      int b = dd[i] >> SH;
      reorder[lscan[b] + rk[i]] = make_int2(ss[i], dd[i]);
    }
  }
  __syncthreads();
  for (int j = t; j < tilecnt; j += 256){
    int2 p = reorder[j];
    tmp[lgbase[p.y >> SH] + j] = p;
  }
}

// One block per bucket (256 nodes): per-node offsets via LDS scan (-> rp),
// then scatter src into the bucket's ~16KB col window (single-CU, merges).
__global__ __launch_bounds__(256) void k_csr(const int2* __restrict__ tmp,
    const int* __restrict__ bstart, int* __restrict__ rp, int* __restrict__ col,
    int n, int E){
  __shared__ int lcnt[256];
  __shared__ int sc[256];
  int b = blockIdx.x, t = threadIdx.x;
  int node0 = b << SH;
  int ncnt = min(256, n - node0);
  int be = bstart[b], ee = bstart[b+1];
  lcnt[t] = 0;
  __syncthreads();
  for (int e = be + t; e < ee; e += 256)
    atomicAdd(&lcnt[tmp[e].y - node0], 1);
  __syncthreads();
  int v = lcnt[t];
  sc[t] = v;
  __syncthreads();
  for (int off = 1; off < 256; off <<= 1){
    int x = (t >= off) ? sc[t-off] : 0;
    __syncthreads();
    sc[t] += x;
    __syncthreads();
  }
  int start = be + sc[t] - v;     // exclusive
  lcnt[t] = start;
  if (t < ncnt) rp[node0 + t] = start;
  if (t == 0 && node0 + ncnt == n) rp[n] = E;
  __syncthreads();
  for (int e = be + t; e < ee; e += 256){
    int2 p = tmp[e];
    int pos = atomicAdd(&lcnt[p.y - node0], 1);
    col[pos] = p.x;
  }
}

// ---------------- Attention + aggregate: 4 dsts per wave ----------------
// 16-lane group g owns dst dbase+...+g; lane r owns channels 8r..8r+7.
// Phase 1 (wave-wide): weights for the union edge range packed into LDS as
// int2 {src<<4, w_h}. Phase 2 (per group): per-lane accumulation, no
// cross-lane reductions. Range-split via (dbase, nmax) for profiling split.
template<bool BF16OUT>
__global__ __launch_bounds__(256) void k_attn(
    const unsigned short* __restrict__ XW, const float* __restrict__ AL, const float* __restrict__ AR,
    const int* __restrict__ rp, const int* __restrict__ col,
    const float* __restrict__ bias, void* __restrict__ OUT, int dbase, int nmax)
{
  __shared__ int   ws[4][512];       // per wave: 64 edges x 4 heads x {s<<4, w}
  __shared__ float arsh[4][4][4];    // per wave: 4 dsts' ar (4 heads)
  int wv = threadIdx.x >> 6;
  int lane = threadIdx.x & 63;
  int r = lane & 15, g = lane >> 4, h2 = r >> 2;
  int d0 = dbase + (blockIdx.x*4 + wv)*4;
  if (d0 >= nmax) return;
  int d = d0 + g;
  bool valid = d < nmax;
  int dc = valid ? d : nmax-1;
  int rs = rp[dc];
  int re = valid ? rp[dc+1] : rs;
  float4 ard4 = ((const float4*)AR)[dc];
  if (r == 0) *(float4*)&arsh[wv][g][0] = ard4;
  float4 ald4 = ((const float4*)AL)[dc];
  float alh = h2==0?ald4.x : h2==1?ald4.y : h2==2?ald4.z : ald4.w;
  float arh = h2==0?ard4.x : h2==1?ard4.y : h2==2?ard4.z : ard4.w;
  float tse = alh + arh;
  float eself = __expf(fmaxf(tse, 0.2f*tse));
  const uint4* XW4 = (const uint4*)XW;
  float acc[8];
  {  // self term
    uint4 v = XW4[(size_t)dc*16 + r];
    acc[0] = eself * __uint_as_float(v.x << 16);
    acc[1] = eself * __uint_as_float(v.x & 0xffff0000u);
    acc[2] = eself * __uint_as_float(v.y << 16);
    acc[3] = eself * __uint_as_float(v.y & 0xffff0000u);
    acc[4] = eself * __uint_as_float(v.z << 16);
    acc[5] = eself * __uint_as_float(v.z & 0xffff0000u);
    acc[6] = eself * __uint_as_float(v.w << 16);
    acc[7] = eself * __uint_as_float(v.w & 0xffff0000u);
  }
  int ub0 = rp[d0];
  int ubE = rp[min(d0+4, nmax)];
  int reb = valid ? re : 0x7fffffff;
  int b1 = __shfl(reb, 0, 64);
  int b2 = __shfl(reb, 16, 64);
  int b3 = __shfl(reb, 32, 64);
  int* wsw = ws[wv];
  float zacc = eself;
  for (int cb = ub0; cb < ubE; cb += 64){
    int cnt = min(64, ubE - cb);
    if (lane < cnt){
      int e = cb + lane;
      int s = col[e];
      int eg = (e >= b1) + (e >= b2) + (e >= b3);
      float4 arr = *(const float4*)&arsh[wv][eg][0];
      float4 a = ((const float4*)AL)[s];
      float t0 = a.x + arr.x, t1 = a.y + arr.y, t2 = a.z + arr.z, t3 = a.w + arr.w;
      float w0 = __expf(fmaxf(t0, 0.2f*t0));
      float w1 = __expf(fmaxf(t1, 0.2f*t1));
      float w2 = __expf(fmaxf(t2, 0.2f*t2));
      float w3 = __expf(fmaxf(t3, 0.2f*t3));
      int s4 = s << 4;
      ((int4*)&wsw[lane*8])[0] = make_int4(s4, __float_as_int(w0), s4, __float_as_int(w1));
      ((int4*)&wsw[lane*8])[1] = make_int4(s4, __float_as_int(w2), s4, __float_as_int(w3));
    }
    int jlo = max(rs - cb, 0);
    int jhi = min(re - cb, cnt);
    #pragma unroll 4
    for (int j = jlo; j < jhi; ++j){
      int2 q = *(const int2*)&wsw[j*8 + h2*2];
      float w = __int_as_float(q.y);
      uint4 u = XW4[(unsigned)(q.x + r)];
      acc[0] = fmaf(w, __uint_as_float(u.x << 16), acc[0]);
      acc[1] = fmaf(w, __uint_as_float(u.x & 0xffff0000u), acc[1]);
      acc[2] = fmaf(w, __uint_as_float(u.y << 16), acc[2]);
      acc[3] = fmaf(w, __uint_as_float(u.y & 0xffff0000u), acc[3]);
      acc[4] = fmaf(w, __uint_as_float(u.z << 16), acc[4]);
      acc[5] = fmaf(w, __uint_as_float(u.z & 0xffff0000u), acc[5]);
      acc[6] = fmaf(w, __uint_as_float(u.w << 16), acc[6]);
      acc[7] = fmaf(w, __uint_as_float(u.w & 0xffff0000u), acc[7]);
      zacc += w;
    }
  }
  float rz = 1.f / zacc;
  float4 bb0 = ((const float4*)bias)[r*2];
  float4 bb1 = ((const float4*)bias)[r*2 + 1];
  float o[8];
  o[0] = fmaf(acc[0], rz, bb0.x); o[1] = fmaf(acc[1], rz, bb0.y);
  o[2] = fmaf(acc[2], rz, bb0.z); o[3] = fmaf(acc[3], rz, bb0.w);
  o[4] = fmaf(acc[4], rz, bb1.x); o[5] = fmaf(acc[5], rz, bb1.y);
  o[6] = fmaf(acc[6], rz, bb1.z); o[7] = fmaf(acc[7], rz, bb1.w);
  #pragma unroll
  for (int i = 0; i < 8; i++) o[i] = o[i] > 0.f ? o[i] : 0.f;
  if (valid){
    if (BF16OUT){
      uint4 pk;
      pk.x = (unsigned)f2bf(o[0]) | ((unsigned)f2bf(o[1]) << 16);
      pk.y = (unsigned)f2bf(o[2]) | ((unsigned)f2bf(o[3]) << 16);
      pk.z = (unsigned)f2bf(o[4]) | ((unsigned)f2bf(o[5]) << 16);
      pk.w = (unsigned)f2bf(o[6]) | ((unsigned)f2bf(o[7]) << 16);
      ((uint4*)OUT)[(size_t)d*16 + r] = pk;
    } else {
      float4 f0; f0.x = o[0]; f0.y = o[1]; f0.z = o[2]; f0.w = o[3];
      float4 f1; f1.x = o[4]; f1.y = o[5]; f1.z = o[6]; f1.w = o[7];
      ((float4*)OUT)[(size_t)d*32 + r*2]     = f0;
      ((float4*)OUT)[(size_t)d*32 + r*2 + 1] = f1;
    }
  }
}

// ---------------- pooling + MLP head ----------------
// R12: 64 slices/graph (4096 blocks) — R11 profile: 8 slices = 8.8% occupancy,
// latency-bound at 431 GB/s. ~24 rows/block now; one atomic per thread.
__global__ __launch_bounds__(128) void k_pool(const float* __restrict__ H,
                                              const int* __restrict__ gstart,
                                              float* __restrict__ psum){
  int g = blockIdx.x >> 6, slice = blockIdx.x & (PSL-1), t = threadIdx.x;
  int s0 = gstart[g], s1 = gstart[g+1];
  int cntg = s1 - s0;
  int chunk = (cntg + PSL-1) / PSL;
  int lo = s0 + slice*chunk;
  int hi = min(lo + chunk, s1);
  if (lo >= hi) return;
  float sum = 0.f;
  for (int i = lo; i < hi; i++) sum += H[(size_t)i*128 + t];
  atomicAdd(&psum[g*128 + t], sum);
}

__global__ __launch_bounds__(128) void k_mlp(const float* __restrict__ psum,
                       const int* __restrict__ gstart,
                       const float* __restrict__ w1, const float* __restrict__ b1,
                       const float* __restrict__ w2, const float* __restrict__ b2,
                       float* __restrict__ out)
{
  __shared__ float p[128];
  __shared__ float gsh[128];
  __shared__ float lg[10];
  int g = blockIdx.x, t = threadIdx.x;
  float c = fmaxf((float)(gstart[g+1] - gstart[g]), 1.f);
  p[t] = psum[g*128 + t] / c;
  __syncthreads();
  float acc = b1[t];
  for (int k = 0; k < 128; k++) acc = fmaf(p[k], w1[k*128 + t], acc);
  gsh[t] = acc > 0.f ? acc : 0.f;
  __syncthreads();
  if (t < 10){
    float a = b2[t];
    for (int k = 0; k < 128; k++) a = fmaf(gsh[k], w2[k*10 + t], a);
    lg[t] = a;
  }
  __syncthreads();
  if (t < 10){
    float mx = lg[0];
    for (int c2 = 1; c2 < 10; c2++) mx = fmaxf(mx, lg[c2]);
    float se = 0.f;
    for (int c2 = 0; c2 < 10; c2++) se += __expf(lg[c2] - mx);
    out[g*10 + t] = lg[t] - mx - logf(se);
  }
}

extern "C" void kernel_launch(void* const* d_in, const int* in_sizes, int n_in,
                              void* d_out, int out_size, void* d_ws, size_t ws_size,
                              hipStream_t stream)
{
  const float* x    = (const float*)d_in[0];
  const int* eidx   = (const int*)d_in[1];
  const int* batch  = (const int*)d_in[2];
  const float* W[3]  = {(const float*)d_in[3], (const float*)d_in[7],  (const float*)d_in[11]};
  const float* al[3] = {(const float*)d_in[4], (const float*)d_in[8],  (const float*)d_in[12]};
  const float* ar[3] = {(const float*)d_in[5], (const float*)d_in[9],  (const float*)d_in[13]};
  const float* bs[3] = {(const float*)d_in[6], (const float*)d_in[10], (const float*)d_in[14]};
  const float* l1w = (const float*)d_in[15];
  const float* l1b = (const float*)d_in[16];
  const float* l2w = (const float*)d_in[17];
  const float* l2b = (const float*)d_in[18];
  int E = in_sizes[1] / 2;
  int n = in_sizes[2];            // 100000
  const int* srcp = eidx;
  const int* dstp = eidx + E;
  int NB = (n + 255) >> SH;       // 391 buckets (<=512)

  char* wsp = (char*)d_ws;
  auto alloc = [&](size_t bytes){ void* p = (void*)wsp; wsp += (bytes + 255) & ~(size_t)255; return p; };
  unsigned short* xw   = (unsigned short*)alloc((size_t)n*128*2);  // 25.6 MB bf16
  unsigned short* hbuf = (unsigned short*)alloc((size_t)n*128*2);  // 25.6 MB bf16
  float* ALb  = (float*)alloc((size_t)n*4*4);
  float* ARb  = (float*)alloc((size_t)n*4*4);
  int* rp     = (int*)alloc((size_t)(n+1)*4);
  int* col    = (int*)alloc((size_t)E*4);          // 6.4 MB
  int2* tmp   = (int2*)alloc((size_t)E*8);         // 12.8 MB bucketed pairs
  int* bcnt   = (int*)alloc(512*4);
  int* bstart = (int*)alloc(513*4);
  int* bfill  = (int*)alloc(512*4);
  float* psum = (float*)alloc(64*128*4);
  int* gstart = (int*)alloc(65*4);

  float* outlog = (float*)d_out;
  float* h3     = (float*)d_out + 64*10;

  int nparts = (E + TILE - 1) / TILE;   // 391

  k_init<<<1, 256, 0, stream>>>(bcnt, psum);
  // fused: bucket histogram + layer-1 GEMM (independent, co-resident)
  k_fuse1<<<nparts + 768, 256, 0, stream>>>(dstp, bcnt, E, nparts,
                                            x, W[0], al[0], ar[0], xw, ALb, ARb, n);
  k_bscan<<<2, 256, 0, stream>>>(bcnt, bstart, bfill, NB, E, batch, gstart, n);
  k_part <<<nparts, 256, 0, stream>>>(srcp, dstp, bfill, tmp, E);
  k_csr  <<<NB, 256, 0, stream>>>(tmp, bstart, rp, col, n, E);

  // attn split into two half-range dispatches (profiling visibility + same work)
  int half = ((n/2) + 15) & ~15;           // group-of-16 aligned
  int ab1 = (half + 15) / 16;
  int ab2 = (n - half + 15) / 16;

  // layer 1 attention (xw ready from fuse1)
  k_attn<true><<<ab1, 256, 0, stream>>>(xw, ALb, ARb, rp, col, bs[0], hbuf, 0, half);
  k_attn<true><<<ab2, 256, 0, stream>>>(xw, ALb, ARb, rp, col, bs[0], hbuf, half, n);
  // layer 2
  k_gemm<true><<<768, 256, 0, stream>>>(hbuf, W[1], al[1], ar[1], xw, ALb, ARb, n);
  k_attn<true><<<ab1, 256, 0, stream>>>(xw, ALb, ARb, rp, col, bs[1], hbuf, 0, half);
  k_attn<true><<<ab2, 256, 0, stream>>>(xw, ALb, ARb, rp, col, bs[1], hbuf, half, n);
  // layer 3 -> fp32 straight into d_out
  k_gemm<true><<<768, 256, 0, stream>>>(hbuf, W[2], al[2], ar[2], xw, ALb, ARb, n);
  k_attn<false><<<ab1, 256, 0, stream>>>(xw, ALb, ARb, rp, col, bs[2], h3, 0, half);
  k_attn<false><<<ab2, 256, 0, stream>>>(xw, ALb, ARb, rp, col, bs[2], h3, half, n);

  k_pool<<<64*PSL, 128, 0, stream>>>(h3, gstart, psum);
  k_mlp <<<64, 128, 0, stream>>>(psum, gstart, l1w, l1b, l2w, l2b, outlog);
}

// Round 7
// 518.466 us; speedup vs baseline: 1.1291x; 1.0376x over previous
//
#include <hip/hip_runtime.h>
#include <math.h>

// GAT 3-layer, MI355X. Round 13:
// GEMM restructured (R12 profile: fuse1 50us, occ 21%, LDS 50KB, 4 bars/tile):
//  - W^T pre-transposed to global bf16 ONCE (fused into k_init blocks 1..192);
//    MFMA B-fragments read straight from global (32KB, L1/L2-hot). No W staging.
//  - Separate 17KB X / C LDS buffers -> 2 barriers/tile, LDS 50->35KB,
//    4 blocks/CU (was 3), grid 768->1024.
// attn stays half-split one more round for profile visibility.

#define LRELU(x) ((x) > 0.f ? (x) : 0.2f*(x))
#define SH 8          // bucket = dst >> 8 (256 nodes per bucket)
#define TILE 4096
#define EPT 16
#define PSL 64        // pool slices per graph

typedef __attribute__((ext_vector_type(8))) short s16x8;
typedef __attribute__((ext_vector_type(4))) float f32x4;

__device__ inline unsigned short f2bf(float f){
  unsigned u = __float_as_uint(f);
  u += 0x7fff + ((u >> 16) & 1);   // round-to-nearest-even
  return (unsigned short)(u >> 16);
}

// ---------------- init: zero bcnt + psum; transpose W1..W3 -> bf16 ------
__global__ void k_init(int* __restrict__ bcnt, float* __restrict__ psum,
                       const float* __restrict__ W0, const float* __restrict__ W1,
                       const float* __restrict__ W2, unsigned short* __restrict__ wt3){
  int t = threadIdx.x;
  if (blockIdx.x == 0){
    bcnt[t] = 0; bcnt[256 + t] = 0;
    for (int i = t; i < 8192; i += 256) psum[i] = 0.f;
    return;
  }
  int e = ((int)blockIdx.x - 1)*256 + t;   // 0..49151
  int layer = e >> 14, rem = e & 16383;
  int k = rem >> 7, nn = rem & 127;
  const float* Ws = layer == 0 ? W0 : (layer == 1 ? W1 : W2);
  wt3[layer*16384 + nn*128 + k] = f2bf(Ws[k*128 + nn]);
}

// ---------------- MFMA bf16 GEMM body (shared by k_gemm / k_fuse1) -------
// Block 256 (4 waves). Tile 64 rows x 128 cols, K=128. Wave w owns cols
// [32w, 32w+32). B-fragments from GLOBAL W^T bf16 (L1-hot, no staging).
// X staged in Xl; acc lands in Cl -> coalesced xw store + local al/ar dot.
template<bool BF16IN>
__device__ __forceinline__ void gemm_body(
    unsigned short* Xl, unsigned short* Cl,
    const void* __restrict__ Xv, const unsigned short* __restrict__ Wtg,
    const float* __restrict__ attl, const float* __restrict__ attr,
    unsigned short* __restrict__ XW, float* __restrict__ AL, float* __restrict__ AR,
    int n, int bid, int gstride)
{
  int t = threadIdx.x;
  int lane = t & 63, w = t >> 6;
  int l15 = lane & 15, quad = lane >> 4;
  int ntiles = (n + 63) >> 6;
  int r_ = t >> 2, seg = t & 3;
  const unsigned short* Bp0 = Wtg + (w*32 + l15)*128 + quad*8;
  const unsigned short* Bp1 = Bp0 + 16*128;
  for (int tile = bid; tile < ntiles; tile += gstride){
    int row0 = tile << 6;
    {  // stage X tile as bf16 (Xl free here: all reads done before prev bar2)
      int grow = row0 + r_;
      unsigned short* dp = &Xl[r_*136 + seg*32];
      if (grow < n){
        if (BF16IN){
          const uint4* gp = (const uint4*)((const unsigned short*)Xv + (size_t)grow*128 + seg*32);
          #pragma unroll
          for (int i = 0; i < 4; i++) ((uint4*)dp)[i] = gp[i];
        } else {
          const float4* gp = (const float4*)((const float*)Xv + (size_t)grow*128 + seg*32);
          #pragma unroll
          for (int i = 0; i < 8; i++){
            float4 v = gp[i];
            ((unsigned*)dp)[i*2]   = (unsigned)f2bf(v.x) | ((unsigned)f2bf(v.y) << 16);
            ((unsigned*)dp)[i*2+1] = (unsigned)f2bf(v.z) | ((unsigned)f2bf(v.w) << 16);
          }
        }
      } else {
        #pragma unroll
        for (int i = 0; i < 4; i++) ((uint4*)dp)[i] = make_uint4(0,0,0,0);
      }
    }
    __syncthreads();   // X visible; prev-tile Cl fully read
    f32x4 acc[4][2];
    #pragma unroll
    for (int rt = 0; rt < 4; rt++){ acc[rt][0] = (f32x4){0,0,0,0}; acc[rt][1] = (f32x4){0,0,0,0}; }
    #pragma unroll
    for (int ks = 0; ks < 4; ks++){
      s16x8 b0 = *(const s16x8*)(Bp0 + ks*32);
      s16x8 b1 = *(const s16x8*)(Bp1 + ks*32);
      #pragma unroll
      for (int rt = 0; rt < 4; rt++){
        s16x8 a = *(const s16x8*)&Xl[(rt*16 + l15)*136 + ks*32 + quad*8];
        acc[rt][0] = __builtin_amdgcn_mfma_f32_16x16x32_bf16(a, b0, acc[rt][0], 0, 0, 0);
        acc[rt][1] = __builtin_amdgcn_mfma_f32_16x16x32_bf16(a, b1, acc[rt][1], 0, 0, 0);
      }
    }
    // C layout: col = l15, row = quad*4 + reg -> separate Cl buffer (no bar)
    #pragma unroll
    for (int rt = 0; rt < 4; rt++)
      #pragma unroll
      for (int c2 = 0; c2 < 2; c2++)
        #pragma unroll
        for (int r = 0; r < 4; r++)
          Cl[(rt*16 + quad*4 + r)*136 + w*32 + c2*16 + l15] = f2bf(acc[rt][c2][r]);
    __syncthreads();   // C visible; X fully consumed
    {  // epilogue: thread -> (row r_, head seg)
      int grow = row0 + r_;
      if (grow < n){
        const unsigned short* sp = &Cl[r_*136 + seg*32];
        uint4 uu[4];
        #pragma unroll
        for (int i = 0; i < 4; i++) uu[i] = ((const uint4*)sp)[i];
        unsigned short* gx = XW + (size_t)grow*128 + seg*32;
        #pragma unroll
        for (int i = 0; i < 4; i++) ((uint4*)gx)[i] = uu[i];
        const unsigned* up = (const unsigned*)uu;
        const float4* alp = (const float4*)(attl + seg*32);
        const float4* arp = (const float4*)(attr + seg*32);
        float pl = 0.f, pr = 0.f;
        #pragma unroll
        for (int i = 0; i < 8; i++){
          unsigned ua = up[i*2], ub = up[i*2+1];
          float x0 = __uint_as_float(ua << 16);
          float x1 = __uint_as_float(ua & 0xffff0000u);
          float x2 = __uint_as_float(ub << 16);
          float x3 = __uint_as_float(ub & 0xffff0000u);
          float4 av = alp[i];
          float4 rv = arp[i];
          pl += x0*av.x + x1*av.y + x2*av.z + x3*av.w;
          pr += x0*rv.x + x1*rv.y + x2*rv.z + x3*rv.w;
        }
        AL[grow*4 + seg] = pl;
        AR[grow*4 + seg] = pr;
      }
    }
  }
}

template<bool BF16IN>
__global__ __launch_bounds__(256) void k_gemm(
    const void* __restrict__ Xv, const unsigned short* __restrict__ Wtg,
    const float* __restrict__ attl, const float* __restrict__ attr,
    unsigned short* __restrict__ XW, float* __restrict__ AL, float* __restrict__ AR, int n)
{
  __shared__ unsigned short Xl[64*136];
  __shared__ unsigned short Cl[64*136];
  gemm_body<BF16IN>(Xl, Cl, Xv, Wtg, attl, attr, XW, AL, AR, n, blockIdx.x, gridDim.x);
}

// ---------------- fused: bucket histogram (blocks < nparts) + GEMM-1 ----
__global__ __launch_bounds__(256) void k_fuse1(
    const int* __restrict__ dst, int* __restrict__ bcnt, int E, int nparts,
    const float* __restrict__ X, const unsigned short* __restrict__ Wtg,
    const float* __restrict__ attl, const float* __restrict__ attr,
    unsigned short* __restrict__ XW, float* __restrict__ AL, float* __restrict__ AR, int n)
{
  __shared__ unsigned short Xl[64*136];
  __shared__ unsigned short Cl[64*136];
  if ((int)blockIdx.x < nparts){
    int* lh = (int*)Xl;     // alias histogram onto Xl
    int t = threadIdx.x;
    for (int j = t; j < 512; j += 256) lh[j] = 0;
    __syncthreads();
    int base = blockIdx.x * TILE;
    int lim = min(base + TILE, E);
    for (int e = base + t; e < lim; e += 256)
      atomicAdd(&lh[dst[e] >> SH], 1);
    __syncthreads();
    for (int j = t; j < 512; j += 256){
      int v = lh[j];
      if (v) atomicAdd(&bcnt[j], v);
    }
    return;
  }
  gemm_body<false>(Xl, Cl, X, Wtg, attl, attr, XW, AL, AR, n,
                   (int)blockIdx.x - nparts, (int)gridDim.x - nparts);
}

// ---------------- bucket scan (block 0) + graph bounds (block 1) --------
__global__ __launch_bounds__(256) void k_bscan(const int* __restrict__ bcnt,
    int* __restrict__ bstart, int* __restrict__ bfill, int NB, int E,
    const int* __restrict__ batch, int* __restrict__ gstart, int n){
  int t = threadIdx.x;
  if (blockIdx.x == 1){
    int g = t;
    if (g > 64) return;
    int lo = 0, hi = n;
    while (lo < hi){
      int mid = (lo + hi) >> 1;
      if (batch[mid] < g) lo = mid + 1; else hi = mid;
    }
    gstart[g] = lo;
    return;
  }
  __shared__ int c[512];
  __shared__ int ps[256];
  for (int j = t; j < 512; j += 256) c[j] = (j < NB) ? bcnt[j] : 0;
  __syncthreads();
  int b0 = 2*t;
  int v0 = c[b0], v1 = c[b0+1];
  int ts = v0 + v1;
  ps[t] = ts; __syncthreads();
  for (int off = 1; off < 256; off <<= 1){
    int x = (t >= off) ? ps[t-off] : 0; __syncthreads();
    ps[t] += x; __syncthreads();
  }
  int pre = ps[t] - ts;
  if (b0   < NB){ bstart[b0]   = pre;    bfill[b0]   = pre; }
  if (b0+1 < NB){ bstart[b0+1] = pre+v0; bfill[b0+1] = pre+v0; }
  if (t == 0) bstart[NB] = E;
}

// LDS multi-split: tile of 4096 edges ranked by bucket, flushed as
// bucket-contiguous runs (~10-edge bursts at SH=8).
__global__ __launch_bounds__(256) void k_part(const int* __restrict__ src,
    const int* __restrict__ dst, int* __restrict__ bfill,
    int2* __restrict__ tmp, int E){
  __shared__ int2 reorder[TILE];
  __shared__ int lhist[512], lscan[512], lgbase[512];
  __shared__ int ps[256];
  int t = threadIdx.x;
  int tb = blockIdx.x * TILE;
  int tilecnt = min(TILE, E - tb);
  for (int j = t; j < 512; j += 256) lhist[j] = 0;
  __syncthreads();
  int ss[EPT], dd[EPT], rk[EPT];
  #pragma unroll
  for (int i = 0; i < EPT; i++){
    int e = tb + t + i*256;
    if (e < E){
      ss[i] = src[e]; dd[i] = dst[e];
      rk[i] = atomicAdd(&lhist[dd[i] >> SH], 1);
    }
  }
  __syncthreads();
  int b0 = 2*t;
  int v0 = lhist[b0], v1 = lhist[b0+1];
  int ts = v0 + v1;
  ps[t] = ts; __syncthreads();
  for (int off = 1; off < 256; off <<= 1){
    int x = (t >= off) ? ps[t-off] : 0; __syncthreads();
    ps[t] += x; __syncthreads();
  }
  int pre = ps[t] - ts;
  int ex0 = pre, ex1 = pre + v0;
  lscan[b0] = ex0; lscan[b0+1] = ex1;
  if (v0 > 0){ int gb = atomicAdd(&bfill[b0],   v0); lgbase[b0]   = gb - ex0; }
  if (v1 > 0){ int gb = atomicAdd(&bfill[b0+1], v1); lgbase[b0+1] = gb - ex1; }
  __syncthreads();
  #pragma unroll
  for (int i = 0; i < EPT; i++){
    int e = tb + t + i*256;
    if (e < E){
      int b = dd[i] >> SH;
      reorder[lscan[b] + rk[i]] = make_int2(ss[i], dd[i]);
    }
  }
  __syncthreads();
  for (int j = t; j < tilecnt; j += 256){
    int2 p = reorder[j];
    tmp[lgbase[p.y >> SH] + j] = p;
  }
}

// One block per bucket (256 nodes): per-node offsets via LDS scan (-> rp),
// then scatter src into the bucket's ~16KB col window (single-CU, merges).
__global__ __launch_bounds__(256) void k_csr(const int2* __restrict__ tmp,
    const int* __restrict__ bstart, int* __restrict__ rp, int* __restrict__ col,
    int n, int E){
  __shared__ int lcnt[256];
  __shared__ int sc[256];
  int b = blockIdx.x, t = threadIdx.x;
  int node0 = b << SH;
  int ncnt = min(256, n - node0);
  int be = bstart[b], ee = bstart[b+1];
  lcnt[t] = 0;
  __syncthreads();
  for (int e = be + t; e < ee; e += 256)
    atomicAdd(&lcnt[tmp[e].y - node0], 1);
  __syncthreads();
  int v = lcnt[t];
  sc[t] = v;
  __syncthreads();
  for (int off = 1; off < 256; off <<= 1){
    int x = (t >= off) ? sc[t-off] : 0;
    __syncthreads();
    sc[t] += x;
    __syncthreads();
  }
  int start = be + sc[t] - v;     // exclusive
  lcnt[t] = start;
  if (t < ncnt) rp[node0 + t] = start;
  if (t == 0 && node0 + ncnt == n) rp[n] = E;
  __syncthreads();
  for (int e = be + t; e < ee; e += 256){
    int2 p = tmp[e];
    int pos = atomicAdd(&lcnt[p.y - node0], 1);
    col[pos] = p.x;
  }
}

// ---------------- Attention + aggregate: 4 dsts per wave ----------------
// 16-lane group g owns dst dbase+...+g; lane r owns channels 8r..8r+7.
// Phase 1 (wave-wide): weights for the union edge range packed into LDS as
// int2 {src<<4, w_h}. Phase 2 (per group): per-lane accumulation, no
// cross-lane reductions. Range-split via (dbase, nmax) for profiling split.
template<bool BF16OUT>
__global__ __launch_bounds__(256) void k_attn(
    const unsigned short* __restrict__ XW, const float* __restrict__ AL, const float* __restrict__ AR,
    const int* __restrict__ rp, const int* __restrict__ col,
    const float* __restrict__ bias, void* __restrict__ OUT, int dbase, int nmax)
{
  __shared__ int   ws[4][512];       // per wave: 64 edges x 4 heads x {s<<4, w}
  __shared__ float arsh[4][4][4];    // per wave: 4 dsts' ar (4 heads)
  int wv = threadIdx.x >> 6;
  int lane = threadIdx.x & 63;
  int r = lane & 15, g = lane >> 4, h2 = r >> 2;
  int d0 = dbase + (blockIdx.x*4 + wv)*4;
  if (d0 >= nmax) return;
  int d = d0 + g;
  bool valid = d < nmax;
  int dc = valid ? d : nmax-1;
  int rs = rp[dc];
  int re = valid ? rp[dc+1] : rs;
  float4 ard4 = ((const float4*)AR)[dc];
  if (r == 0) *(float4*)&arsh[wv][g][0] = ard4;
  float4 ald4 = ((const float4*)AL)[dc];
  float alh = h2==0?ald4.x : h2==1?ald4.y : h2==2?ald4.z : ald4.w;
  float arh = h2==0?ard4.x : h2==1?ard4.y : h2==2?ard4.z : ard4.w;
  float tse = alh + arh;
  float eself = __expf(fmaxf(tse, 0.2f*tse));
  const uint4* XW4 = (const uint4*)XW;
  float acc[8];
  {  // self term
    uint4 v = XW4[(size_t)dc*16 + r];
    acc[0] = eself * __uint_as_float(v.x << 16);
    acc[1] = eself * __uint_as_float(v.x & 0xffff0000u);
    acc[2] = eself * __uint_as_float(v.y << 16);
    acc[3] = eself * __uint_as_float(v.y & 0xffff0000u);
    acc[4] = eself * __uint_as_float(v.z << 16);
    acc[5] = eself * __uint_as_float(v.z & 0xffff0000u);
    acc[6] = eself * __uint_as_float(v.w << 16);
    acc[7] = eself * __uint_as_float(v.w & 0xffff0000u);
  }
  int ub0 = rp[d0];
  int ubE = rp[min(d0+4, nmax)];
  int reb = valid ? re : 0x7fffffff;
  int b1 = __shfl(reb, 0, 64);
  int b2 = __shfl(reb, 16, 64);
  int b3 = __shfl(reb, 32, 64);
  int* wsw = ws[wv];
  float zacc = eself;
  for (int cb = ub0; cb < ubE; cb += 64){
    int cnt = min(64, ubE - cb);
    if (lane < cnt){
      int e = cb + lane;
      int s = col[e];
      int eg = (e >= b1) + (e >= b2) + (e >= b3);
      float4 arr = *(const float4*)&arsh[wv][eg][0];
      float4 a = ((const float4*)AL)[s];
      float t0 = a.x + arr.x, t1 = a.y + arr.y, t2 = a.z + arr.z, t3 = a.w + arr.w;
      float w0 = __expf(fmaxf(t0, 0.2f*t0));
      float w1 = __expf(fmaxf(t1, 0.2f*t1));
      float w2 = __expf(fmaxf(t2, 0.2f*t2));
      float w3 = __expf(fmaxf(t3, 0.2f*t3));
      int s4 = s << 4;
      ((int4*)&wsw[lane*8])[0] = make_int4(s4, __float_as_int(w0), s4, __float_as_int(w1));
      ((int4*)&wsw[lane*8])[1] = make_int4(s4, __float_as_int(w2), s4, __float_as_int(w3));
    }
    int jlo = max(rs - cb, 0);
    int jhi = min(re - cb, cnt);
    #pragma unroll 4
    for (int j = jlo; j < jhi; ++j){
      int2 q = *(const int2*)&wsw[j*8 + h2*2];
      float w = __int_as_float(q.y);
      uint4 u = XW4[(unsigned)(q.x + r)];
      acc[0] = fmaf(w, __uint_as_float(u.x << 16), acc[0]);
      acc[1] = fmaf(w, __uint_as_float(u.x & 0xffff0000u), acc[1]);
      acc[2] = fmaf(w, __uint_as_float(u.y << 16), acc[2]);
      acc[3] = fmaf(w, __uint_as_float(u.y & 0xffff0000u), acc[3]);
      acc[4] = fmaf(w, __uint_as_float(u.z << 16), acc[4]);
      acc[5] = fmaf(w, __uint_as_float(u.z & 0xffff0000u), acc[5]);
      acc[6] = fmaf(w, __uint_as_float(u.w << 16), acc[6]);
      acc[7] = fmaf(w, __uint_as_float(u.w & 0xffff0000u), acc[7]);
      zacc += w;
    }
  }
  float rz = 1.f / zacc;
  float4 bb0 = ((const float4*)bias)[r*2];
  float4 bb1 = ((const float4*)bias)[r*2 + 1];
  float o[8];
  o[0] = fmaf(acc[0], rz, bb0.x); o[1] = fmaf(acc[1], rz, bb0.y);
  o[2] = fmaf(acc[2], rz, bb0.z); o[3] = fmaf(acc[3], rz, bb0.w);
  o[4] = fmaf(acc[4], rz, bb1.x); o[5] = fmaf(acc[5], rz, bb1.y);
  o[6] = fmaf(acc[6], rz, bb1.z); o[7] = fmaf(acc[7], rz, bb1.w);
  #pragma unroll
  for (int i = 0; i < 8; i++) o[i] = o[i] > 0.f ? o[i] : 0.f;
  if (valid){
    if (BF16OUT){
      uint4 pk;
      pk.x = (unsigned)f2bf(o[0]) | ((unsigned)f2bf(o[1]) << 16);
      pk.y = (unsigned)f2bf(o[2]) | ((unsigned)f2bf(o[3]) << 16);
      pk.z = (unsigned)f2bf(o[4]) | ((unsigned)f2bf(o[5]) << 16);
      pk.w = (unsigned)f2bf(o[6]) | ((unsigned)f2bf(o[7]) << 16);
      ((uint4*)OUT)[(size_t)d*16 + r] = pk;
    } else {
      float4 f0; f0.x = o[0]; f0.y = o[1]; f0.z = o[2]; f0.w = o[3];
      float4 f1; f1.x = o[4]; f1.y = o[5]; f1.z = o[6]; f1.w = o[7];
      ((float4*)OUT)[(size_t)d*32 + r*2]     = f0;
      ((float4*)OUT)[(size_t)d*32 + r*2 + 1] = f1;
    }
  }
}

// ---------------- pooling + MLP head ----------------
// 64 slices/graph (4096 blocks): ~24 rows/block, BW-bound (R12 fix).
__global__ __launch_bounds__(128) void k_pool(const float* __restrict__ H,
                                              const int* __restrict__ gstart,
                                              float* __restrict__ psum){
  int g = blockIdx.x >> 6, slice = blockIdx.x & (PSL-1), t = threadIdx.x;
  int s0 = gstart[g], s1 = gstart[g+1];
  int cntg = s1 - s0;
  int chunk = (cntg + PSL-1) / PSL;
  int lo = s0 + slice*chunk;
  int hi = min(lo + chunk, s1);
  if (lo >= hi) return;
  float sum = 0.f;
  for (int i = lo; i < hi; i++) sum += H[(size_t)i*128 + t];
  atomicAdd(&psum[g*128 + t], sum);
}

__global__ __launch_bounds__(128) void k_mlp(const float* __restrict__ psum,
                       const int* __restrict__ gstart,
                       const float* __restrict__ w1, const float* __restrict__ b1,
                       const float* __restrict__ w2, const float* __restrict__ b2,
                       float* __restrict__ out)
{
  __shared__ float p[128];
  __shared__ float gsh[128];
  __shared__ float lg[10];
  int g = blockIdx.x, t = threadIdx.x;
  float c = fmaxf((float)(gstart[g+1] - gstart[g]), 1.f);
  p[t] = psum[g*128 + t] / c;
  __syncthreads();
  float acc = b1[t];
  for (int k = 0; k < 128; k++) acc = fmaf(p[k], w1[k*128 + t], acc);
  gsh[t] = acc > 0.f ? acc : 0.f;
  __syncthreads();
  if (t < 10){
    float a = b2[t];
    for (int k = 0; k < 128; k++) a = fmaf(gsh[k], w2[k*10 + t], a);
    lg[t] = a;
  }
  __syncthreads();
  if (t < 10){
    float mx = lg[0];
    for (int c2 = 1; c2 < 10; c2++) mx = fmaxf(mx, lg[c2]);
    float se = 0.f;
    for (int c2 = 0; c2 < 10; c2++) se += __expf(lg[c2] - mx);
    out[g*10 + t] = lg[t] - mx - logf(se);
  }
}

extern "C" void kernel_launch(void* const* d_in, const int* in_sizes, int n_in,
                              void* d_out, int out_size, void* d_ws, size_t ws_size,
                              hipStream_t stream)
{
  const float* x    = (const float*)d_in[0];
  const int* eidx   = (const int*)d_in[1];
  const int* batch  = (const int*)d_in[2];
  const float* W[3]  = {(const float*)d_in[3], (const float*)d_in[7],  (const float*)d_in[11]};
  const float* al[3] = {(const float*)d_in[4], (const float*)d_in[8],  (const float*)d_in[12]};
  const float* ar[3] = {(const float*)d_in[5], (const float*)d_in[9],  (const float*)d_in[13]};
  const float* bs[3] = {(const float*)d_in[6], (const float*)d_in[10], (const float*)d_in[14]};
  const float* l1w = (const float*)d_in[15];
  const float* l1b = (const float*)d_in[16];
  const float* l2w = (const float*)d_in[17];
  const float* l2b = (const float*)d_in[18];
  int E = in_sizes[1] / 2;
  int n = in_sizes[2];            // 100000
  const int* srcp = eidx;
  const int* dstp = eidx + E;
  int NB = (n + 255) >> SH;       // 391 buckets (<=512)

  char* wsp = (char*)d_ws;
  auto alloc = [&](size_t bytes){ void* p = (void*)wsp; wsp += (bytes + 255) & ~(size_t)255; return p; };
  unsigned short* xw   = (unsigned short*)alloc((size_t)n*128*2);  // 25.6 MB bf16
  unsigned short* hbuf = (unsigned short*)alloc((size_t)n*128*2);  // 25.6 MB bf16
  float* ALb  = (float*)alloc((size_t)n*4*4);
  float* ARb  = (float*)alloc((size_t)n*4*4);
  int* rp     = (int*)alloc((size_t)(n+1)*4);
  int* col    = (int*)alloc((size_t)E*4);          // 6.4 MB
  int2* tmp   = (int2*)alloc((size_t)E*8);         // 12.8 MB bucketed pairs
  int* bcnt   = (int*)alloc(512*4);
  int* bstart = (int*)alloc(513*4);
  int* bfill  = (int*)alloc(512*4);
  float* psum = (float*)alloc(64*128*4);
  int* gstart = (int*)alloc(65*4);
  unsigned short* wt3 = (unsigned short*)alloc(3*16384*2);   // W^T bf16 x3

  float* outlog = (float*)d_out;
  float* h3     = (float*)d_out + 64*10;

  int nparts = (E + TILE - 1) / TILE;   // 391

  k_init<<<193, 256, 0, stream>>>(bcnt, psum, W[0], W[1], W[2], wt3);
  // fused: bucket histogram + layer-1 GEMM (independent, co-resident)
  k_fuse1<<<nparts + 1024, 256, 0, stream>>>(dstp, bcnt, E, nparts,
                                             x, wt3, al[0], ar[0], xw, ALb, ARb, n);
  k_bscan<<<2, 256, 0, stream>>>(bcnt, bstart, bfill, NB, E, batch, gstart, n);
  k_part <<<nparts, 256, 0, stream>>>(srcp, dstp, bfill, tmp, E);
  k_csr  <<<NB, 256, 0, stream>>>(tmp, bstart, rp, col, n, E);

  // attn split into two half-range dispatches (profiling visibility + same work)
  int half = ((n/2) + 15) & ~15;           // group-of-16 aligned
  int ab1 = (half + 15) / 16;
  int ab2 = (n - half + 15) / 16;

  // layer 1 attention (xw ready from fuse1)
  k_attn<true><<<ab1, 256, 0, stream>>>(xw, ALb, ARb, rp, col, bs[0], hbuf, 0, half);
  k_attn<true><<<ab2, 256, 0, stream>>>(xw, ALb, ARb, rp, col, bs[0], hbuf, half, n);
  // layer 2
  k_gemm<true><<<1024, 256, 0, stream>>>(hbuf, wt3 + 16384, al[1], ar[1], xw, ALb, ARb, n);
  k_attn<true><<<ab1, 256, 0, stream>>>(xw, ALb, ARb, rp, col, bs[1], hbuf, 0, half);
  k_attn<true><<<ab2, 256, 0, stream>>>(xw, ALb, ARb, rp, col, bs[1], hbuf, half, n);
  // layer 3 -> fp32 straight into d_out
  k_gemm<true><<<1024, 256, 0, stream>>>(hbuf, wt3 + 32768, al[2], ar[2], xw, ALb, ARb, n);
  k_attn<false><<<ab1, 256, 0, stream>>>(xw, ALb, ARb, rp, col, bs[2], h3, 0, half);
  k_attn<false><<<ab2, 256, 0, stream>>>(xw, ALb, ARb, rp, col, bs[2], h3, half, n);

  k_pool<<<64*PSL, 128, 0, stream>>>(h3, gstart, psum);
  k_mlp <<<64, 128, 0, stream>>>(psum, gstart, l1w, l1b, l2w, l2b, outlog);
}

// Round 8
// 499.666 us; speedup vs baseline: 1.1716x; 1.0376x over previous
//
#include <hip/hip_runtime.h>
#include <math.h>

// GAT 3-layer, MI355X. Round 14:
// - attn re-merged to one dispatch/layer (R13 halves: 2x42.8 vs 76.4 merged,
//   split cost ~9us/layer). Merged attn occupies top-3 slots; #4-5 expose the
//   two largest mid-tier kernels next round.
// - gemm_body: B-fragments hoisted out of the tile loop into registers
//   (8 x s16x8, loaded once). VGPR ~108 stays in 4-blocks/CU bucket.

#define LRELU(x) ((x) > 0.f ? (x) : 0.2f*(x))
#define SH 8          // bucket = dst >> 8 (256 nodes per bucket)
#define TILE 4096
#define EPT 16
#define PSL 64        // pool slices per graph

typedef __attribute__((ext_vector_type(8))) short s16x8;
typedef __attribute__((ext_vector_type(4))) float f32x4;

__device__ inline unsigned short f2bf(float f){
  unsigned u = __float_as_uint(f);
  u += 0x7fff + ((u >> 16) & 1);   // round-to-nearest-even
  return (unsigned short)(u >> 16);
}

// ---------------- init: zero bcnt + psum; transpose W1..W3 -> bf16 ------
__global__ void k_init(int* __restrict__ bcnt, float* __restrict__ psum,
                       const float* __restrict__ W0, const float* __restrict__ W1,
                       const float* __restrict__ W2, unsigned short* __restrict__ wt3){
  int t = threadIdx.x;
  if (blockIdx.x == 0){
    bcnt[t] = 0; bcnt[256 + t] = 0;
    for (int i = t; i < 8192; i += 256) psum[i] = 0.f;
    return;
  }
  int e = ((int)blockIdx.x - 1)*256 + t;   // 0..49151
  int layer = e >> 14, rem = e & 16383;
  int k = rem >> 7, nn = rem & 127;
  const float* Ws = layer == 0 ? W0 : (layer == 1 ? W1 : W2);
  wt3[layer*16384 + nn*128 + k] = f2bf(Ws[k*128 + nn]);
}

// ---------------- MFMA bf16 GEMM body (shared by k_gemm / k_fuse1) -------
// Block 256 (4 waves). Tile 64 rows x 128 cols, K=128. Wave w owns cols
// [32w, 32w+32). B-fragments hoisted to registers ONCE from global W^T bf16.
// X staged in Xl; acc lands in Cl -> coalesced xw store + local al/ar dot.
template<bool BF16IN>
__device__ __forceinline__ void gemm_body(
    unsigned short* Xl, unsigned short* Cl,
    const void* __restrict__ Xv, const unsigned short* __restrict__ Wtg,
    const float* __restrict__ attl, const float* __restrict__ attr,
    unsigned short* __restrict__ XW, float* __restrict__ AL, float* __restrict__ AR,
    int n, int bid, int gstride)
{
  int t = threadIdx.x;
  int lane = t & 63, w = t >> 6;
  int l15 = lane & 15, quad = lane >> 4;
  int ntiles = (n + 63) >> 6;
  int r_ = t >> 2, seg = t & 3;
  const unsigned short* Bp0 = Wtg + (w*32 + l15)*128 + quad*8;
  const unsigned short* Bp1 = Bp0 + 16*128;
  // hoist B fragments: loop-invariant, 8 x s16x8 = 32 VGPRs
  s16x8 b0r[4], b1r[4];
  #pragma unroll
  for (int ks = 0; ks < 4; ks++){
    b0r[ks] = *(const s16x8*)(Bp0 + ks*32);
    b1r[ks] = *(const s16x8*)(Bp1 + ks*32);
  }
  for (int tile = bid; tile < ntiles; tile += gstride){
    int row0 = tile << 6;
    {  // stage X tile as bf16 (Xl free here: all reads done before prev bar2)
      int grow = row0 + r_;
      unsigned short* dp = &Xl[r_*136 + seg*32];
      if (grow < n){
        if (BF16IN){
          const uint4* gp = (const uint4*)((const unsigned short*)Xv + (size_t)grow*128 + seg*32);
          #pragma unroll
          for (int i = 0; i < 4; i++) ((uint4*)dp)[i] = gp[i];
        } else {
          const float4* gp = (const float4*)((const float*)Xv + (size_t)grow*128 + seg*32);
          #pragma unroll
          for (int i = 0; i < 8; i++){
            float4 v = gp[i];
            ((unsigned*)dp)[i*2]   = (unsigned)f2bf(v.x) | ((unsigned)f2bf(v.y) << 16);
            ((unsigned*)dp)[i*2+1] = (unsigned)f2bf(v.z) | ((unsigned)f2bf(v.w) << 16);
          }
        }
      } else {
        #pragma unroll
        for (int i = 0; i < 4; i++) ((uint4*)dp)[i] = make_uint4(0,0,0,0);
      }
    }
    __syncthreads();   // X visible; prev-tile Cl fully read
    f32x4 acc[4][2];
    #pragma unroll
    for (int rt = 0; rt < 4; rt++){ acc[rt][0] = (f32x4){0,0,0,0}; acc[rt][1] = (f32x4){0,0,0,0}; }
    #pragma unroll
    for (int ks = 0; ks < 4; ks++){
      #pragma unroll
      for (int rt = 0; rt < 4; rt++){
        s16x8 a = *(const s16x8*)&Xl[(rt*16 + l15)*136 + ks*32 + quad*8];
        acc[rt][0] = __builtin_amdgcn_mfma_f32_16x16x32_bf16(a, b0r[ks], acc[rt][0], 0, 0, 0);
        acc[rt][1] = __builtin_amdgcn_mfma_f32_16x16x32_bf16(a, b1r[ks], acc[rt][1], 0, 0, 0);
      }
    }
    // C layout: col = l15, row = quad*4 + reg -> separate Cl buffer (no bar)
    #pragma unroll
    for (int rt = 0; rt < 4; rt++)
      #pragma unroll
      for (int c2 = 0; c2 < 2; c2++)
        #pragma unroll
        for (int r = 0; r < 4; r++)
          Cl[(rt*16 + quad*4 + r)*136 + w*32 + c2*16 + l15] = f2bf(acc[rt][c2][r]);
    __syncthreads();   // C visible; X fully consumed
    {  // epilogue: thread -> (row r_, head seg)
      int grow = row0 + r_;
      if (grow < n){
        const unsigned short* sp = &Cl[r_*136 + seg*32];
        uint4 uu[4];
        #pragma unroll
        for (int i = 0; i < 4; i++) uu[i] = ((const uint4*)sp)[i];
        unsigned short* gx = XW + (size_t)grow*128 + seg*32;
        #pragma unroll
        for (int i = 0; i < 4; i++) ((uint4*)gx)[i] = uu[i];
        const unsigned* up = (const unsigned*)uu;
        const float4* alp = (const float4*)(attl + seg*32);
        const float4* arp = (const float4*)(attr + seg*32);
        float pl = 0.f, pr = 0.f;
        #pragma unroll
        for (int i = 0; i < 8; i++){
          unsigned ua = up[i*2], ub = up[i*2+1];
          float x0 = __uint_as_float(ua << 16);
          float x1 = __uint_as_float(ua & 0xffff0000u);
          float x2 = __uint_as_float(ub << 16);
          float x3 = __uint_as_float(ub & 0xffff0000u);
          float4 av = alp[i];
          float4 rv = arp[i];
          pl += x0*av.x + x1*av.y + x2*av.z + x3*av.w;
          pr += x0*rv.x + x1*rv.y + x2*rv.z + x3*rv.w;
        }
        AL[grow*4 + seg] = pl;
        AR[grow*4 + seg] = pr;
      }
    }
  }
}

template<bool BF16IN>
__global__ __launch_bounds__(256) void k_gemm(
    const void* __restrict__ Xv, const unsigned short* __restrict__ Wtg,
    const float* __restrict__ attl, const float* __restrict__ attr,
    unsigned short* __restrict__ XW, float* __restrict__ AL, float* __restrict__ AR, int n)
{
  __shared__ unsigned short Xl[64*136];
  __shared__ unsigned short Cl[64*136];
  gemm_body<BF16IN>(Xl, Cl, Xv, Wtg, attl, attr, XW, AL, AR, n, blockIdx.x, gridDim.x);
}

// ---------------- fused: bucket histogram (blocks < nparts) + GEMM-1 ----
__global__ __launch_bounds__(256) void k_fuse1(
    const int* __restrict__ dst, int* __restrict__ bcnt, int E, int nparts,
    const float* __restrict__ X, const unsigned short* __restrict__ Wtg,
    const float* __restrict__ attl, const float* __restrict__ attr,
    unsigned short* __restrict__ XW, float* __restrict__ AL, float* __restrict__ AR, int n)
{
  __shared__ unsigned short Xl[64*136];
  __shared__ unsigned short Cl[64*136];
  if ((int)blockIdx.x < nparts){
    int* lh = (int*)Xl;     // alias histogram onto Xl
    int t = threadIdx.x;
    for (int j = t; j < 512; j += 256) lh[j] = 0;
    __syncthreads();
    int base = blockIdx.x * TILE;
    int lim = min(base + TILE, E);
    for (int e = base + t; e < lim; e += 256)
      atomicAdd(&lh[dst[e] >> SH], 1);
    __syncthreads();
    for (int j = t; j < 512; j += 256){
      int v = lh[j];
      if (v) atomicAdd(&bcnt[j], v);
    }
    return;
  }
  gemm_body<false>(Xl, Cl, X, Wtg, attl, attr, XW, AL, AR, n,
                   (int)blockIdx.x - nparts, (int)gridDim.x - nparts);
}

// ---------------- bucket scan (block 0) + graph bounds (block 1) --------
__global__ __launch_bounds__(256) void k_bscan(const int* __restrict__ bcnt,
    int* __restrict__ bstart, int* __restrict__ bfill, int NB, int E,
    const int* __restrict__ batch, int* __restrict__ gstart, int n){
  int t = threadIdx.x;
  if (blockIdx.x == 1){
    int g = t;
    if (g > 64) return;
    int lo = 0, hi = n;
    while (lo < hi){
      int mid = (lo + hi) >> 1;
      if (batch[mid] < g) lo = mid + 1; else hi = mid;
    }
    gstart[g] = lo;
    return;
  }
  __shared__ int c[512];
  __shared__ int ps[256];
  for (int j = t; j < 512; j += 256) c[j] = (j < NB) ? bcnt[j] : 0;
  __syncthreads();
  int b0 = 2*t;
  int v0 = c[b0], v1 = c[b0+1];
  int ts = v0 + v1;
  ps[t] = ts; __syncthreads();
  for (int off = 1; off < 256; off <<= 1){
    int x = (t >= off) ? ps[t-off] : 0; __syncthreads();
    ps[t] += x; __syncthreads();
  }
  int pre = ps[t] - ts;
  if (b0   < NB){ bstart[b0]   = pre;    bfill[b0]   = pre; }
  if (b0+1 < NB){ bstart[b0+1] = pre+v0; bfill[b0+1] = pre+v0; }
  if (t == 0) bstart[NB] = E;
}

// LDS multi-split: tile of 4096 edges ranked by bucket, flushed as
// bucket-contiguous runs (~10-edge bursts at SH=8).
__global__ __launch_bounds__(256) void k_part(const int* __restrict__ src,
    const int* __restrict__ dst, int* __restrict__ bfill,
    int2* __restrict__ tmp, int E){
  __shared__ int2 reorder[TILE];
  __shared__ int lhist[512], lscan[512], lgbase[512];
  __shared__ int ps[256];
  int t = threadIdx.x;
  int tb = blockIdx.x * TILE;
  int tilecnt = min(TILE, E - tb);
  for (int j = t; j < 512; j += 256) lhist[j] = 0;
  __syncthreads();
  int ss[EPT], dd[EPT], rk[EPT];
  #pragma unroll
  for (int i = 0; i < EPT; i++){
    int e = tb + t + i*256;
    if (e < E){
      ss[i] = src[e]; dd[i] = dst[e];
      rk[i] = atomicAdd(&lhist[dd[i] >> SH], 1);
    }
  }
  __syncthreads();
  int b0 = 2*t;
  int v0 = lhist[b0], v1 = lhist[b0+1];
  int ts = v0 + v1;
  ps[t] = ts; __syncthreads();
  for (int off = 1; off < 256; off <<= 1){
    int x = (t >= off) ? ps[t-off] : 0; __syncthreads();
    ps[t] += x; __syncthreads();
  }
  int pre = ps[t] - ts;
  int ex0 = pre, ex1 = pre + v0;
  lscan[b0] = ex0; lscan[b0+1] = ex1;
  if (v0 > 0){ int gb = atomicAdd(&bfill[b0],   v0); lgbase[b0]   = gb - ex0; }
  if (v1 > 0){ int gb = atomicAdd(&bfill[b0+1], v1); lgbase[b0+1] = gb - ex1; }
  __syncthreads();
  #pragma unroll
  for (int i = 0; i < EPT; i++){
    int e = tb + t + i*256;
    if (e < E){
      int b = dd[i] >> SH;
      reorder[lscan[b] + rk[i]] = make_int2(ss[i], dd[i]);
    }
  }
  __syncthreads();
  for (int j = t; j < tilecnt; j += 256){
    int2 p = reorder[j];
    tmp[lgbase[p.y >> SH] + j] = p;
  }
}

// One block per bucket (256 nodes): per-node offsets via LDS scan (-> rp),
// then scatter src into the bucket's ~16KB col window (single-CU, merges).
__global__ __launch_bounds__(256) void k_csr(const int2* __restrict__ tmp,
    const int* __restrict__ bstart, int* __restrict__ rp, int* __restrict__ col,
    int n, int E){
  __shared__ int lcnt[256];
  __shared__ int sc[256];
  int b = blockIdx.x, t = threadIdx.x;
  int node0 = b << SH;
  int ncnt = min(256, n - node0);
  int be = bstart[b], ee = bstart[b+1];
  lcnt[t] = 0;
  __syncthreads();
  for (int e = be + t; e < ee; e += 256)
    atomicAdd(&lcnt[tmp[e].y - node0], 1);
  __syncthreads();
  int v = lcnt[t];
  sc[t] = v;
  __syncthreads();
  for (int off = 1; off < 256; off <<= 1){
    int x = (t >= off) ? sc[t-off] : 0;
    __syncthreads();
    sc[t] += x;
    __syncthreads();
  }
  int start = be + sc[t] - v;     // exclusive
  lcnt[t] = start;
  if (t < ncnt) rp[node0 + t] = start;
  if (t == 0 && node0 + ncnt == n) rp[n] = E;
  __syncthreads();
  for (int e = be + t; e < ee; e += 256){
    int2 p = tmp[e];
    int pos = atomicAdd(&lcnt[p.y - node0], 1);
    col[pos] = p.x;
  }
}

// ---------------- Attention + aggregate: 4 dsts per wave ----------------
// 16-lane group g owns dst d0+g; lane r owns channels 8r..8r+7.
// Phase 1 (wave-wide): weights for the union edge range packed into LDS as
// int2 {src<<4, w_h}. Phase 2 (per group): per-lane accumulation, no
// cross-lane reductions.
template<bool BF16OUT>
__global__ __launch_bounds__(256) void k_attn(
    const unsigned short* __restrict__ XW, const float* __restrict__ AL, const float* __restrict__ AR,
    const int* __restrict__ rp, const int* __restrict__ col,
    const float* __restrict__ bias, void* __restrict__ OUT, int dbase, int nmax)
{
  __shared__ int   ws[4][512];       // per wave: 64 edges x 4 heads x {s<<4, w}
  __shared__ float arsh[4][4][4];    // per wave: 4 dsts' ar (4 heads)
  int wv = threadIdx.x >> 6;
  int lane = threadIdx.x & 63;
  int r = lane & 15, g = lane >> 4, h2 = r >> 2;
  int d0 = dbase + (blockIdx.x*4 + wv)*4;
  if (d0 >= nmax) return;
  int d = d0 + g;
  bool valid = d < nmax;
  int dc = valid ? d : nmax-1;
  int rs = rp[dc];
  int re = valid ? rp[dc+1] : rs;
  float4 ard4 = ((const float4*)AR)[dc];
  if (r == 0) *(float4*)&arsh[wv][g][0] = ard4;
  float4 ald4 = ((const float4*)AL)[dc];
  float alh = h2==0?ald4.x : h2==1?ald4.y : h2==2?ald4.z : ald4.w;
  float arh = h2==0?ard4.x : h2==1?ard4.y : h2==2?ard4.z : ard4.w;
  float tse = alh + arh;
  float eself = __expf(fmaxf(tse, 0.2f*tse));
  const uint4* XW4 = (const uint4*)XW;
  float acc[8];
  {  // self term
    uint4 v = XW4[(size_t)dc*16 + r];
    acc[0] = eself * __uint_as_float(v.x << 16);
    acc[1] = eself * __uint_as_float(v.x & 0xffff0000u);
    acc[2] = eself * __uint_as_float(v.y << 16);
    acc[3] = eself * __uint_as_float(v.y & 0xffff0000u);
    acc[4] = eself * __uint_as_float(v.z << 16);
    acc[5] = eself * __uint_as_float(v.z & 0xffff0000u);
    acc[6] = eself * __uint_as_float(v.w << 16);
    acc[7] = eself * __uint_as_float(v.w & 0xffff0000u);
  }
  int ub0 = rp[d0];
  int ubE = rp[min(d0+4, nmax)];
  int reb = valid ? re : 0x7fffffff;
  int b1 = __shfl(reb, 0, 64);
  int b2 = __shfl(reb, 16, 64);
  int b3 = __shfl(reb, 32, 64);
  int* wsw = ws[wv];
  float zacc = eself;
  for (int cb = ub0; cb < ubE; cb += 64){
    int cnt = min(64, ubE - cb);
    if (lane < cnt){
      int e = cb + lane;
      int s = col[e];
      int eg = (e >= b1) + (e >= b2) + (e >= b3);
      float4 arr = *(const float4*)&arsh[wv][eg][0];
      float4 a = ((const float4*)AL)[s];
      float t0 = a.x + arr.x, t1 = a.y + arr.y, t2 = a.z + arr.z, t3 = a.w + arr.w;
      float w0 = __expf(fmaxf(t0, 0.2f*t0));
      float w1 = __expf(fmaxf(t1, 0.2f*t1));
      float w2 = __expf(fmaxf(t2, 0.2f*t2));
      float w3 = __expf(fmaxf(t3, 0.2f*t3));
      int s4 = s << 4;
      ((int4*)&wsw[lane*8])[0] = make_int4(s4, __float_as_int(w0), s4, __float_as_int(w1));
      ((int4*)&wsw[lane*8])[1] = make_int4(s4, __float_as_int(w2), s4, __float_as_int(w3));
    }
    int jlo = max(rs - cb, 0);
    int jhi = min(re - cb, cnt);
    #pragma unroll 4
    for (int j = jlo; j < jhi; ++j){
      int2 q = *(const int2*)&wsw[j*8 + h2*2];
      float w = __int_as_float(q.y);
      uint4 u = XW4[(unsigned)(q.x + r)];
      acc[0] = fmaf(w, __uint_as_float(u.x << 16), acc[0]);
      acc[1] = fmaf(w, __uint_as_float(u.x & 0xffff0000u), acc[1]);
      acc[2] = fmaf(w, __uint_as_float(u.y << 16), acc[2]);
      acc[3] = fmaf(w, __uint_as_float(u.y & 0xffff0000u), acc[3]);
      acc[4] = fmaf(w, __uint_as_float(u.z << 16), acc[4]);
      acc[5] = fmaf(w, __uint_as_float(u.z & 0xffff0000u), acc[5]);
      acc[6] = fmaf(w, __uint_as_float(u.w << 16), acc[6]);
      acc[7] = fmaf(w, __uint_as_float(u.w & 0xffff0000u), acc[7]);
      zacc += w;
    }
  }
  float rz = 1.f / zacc;
  float4 bb0 = ((const float4*)bias)[r*2];
  float4 bb1 = ((const float4*)bias)[r*2 + 1];
  float o[8];
  o[0] = fmaf(acc[0], rz, bb0.x); o[1] = fmaf(acc[1], rz, bb0.y);
  o[2] = fmaf(acc[2], rz, bb0.z); o[3] = fmaf(acc[3], rz, bb0.w);
  o[4] = fmaf(acc[4], rz, bb1.x); o[5] = fmaf(acc[5], rz, bb1.y);
  o[6] = fmaf(acc[6], rz, bb1.z); o[7] = fmaf(acc[7], rz, bb1.w);
  #pragma unroll
  for (int i = 0; i < 8; i++) o[i] = o[i] > 0.f ? o[i] : 0.f;
  if (valid){
    if (BF16OUT){
      uint4 pk;
      pk.x = (unsigned)f2bf(o[0]) | ((unsigned)f2bf(o[1]) << 16);
      pk.y = (unsigned)f2bf(o[2]) | ((unsigned)f2bf(o[3]) << 16);
      pk.z = (unsigned)f2bf(o[4]) | ((unsigned)f2bf(o[5]) << 16);
      pk.w = (unsigned)f2bf(o[6]) | ((unsigned)f2bf(o[7]) << 16);
      ((uint4*)OUT)[(size_t)d*16 + r] = pk;
    } else {
      float4 f0; f0.x = o[0]; f0.y = o[1]; f0.z = o[2]; f0.w = o[3];
      float4 f1; f1.x = o[4]; f1.y = o[5]; f1.z = o[6]; f1.w = o[7];
      ((float4*)OUT)[(size_t)d*32 + r*2]     = f0;
      ((float4*)OUT)[(size_t)d*32 + r*2 + 1] = f1;
    }
  }
}

// ---------------- pooling + MLP head ----------------
// 64 slices/graph (4096 blocks): ~24 rows/block, BW-bound (R12 fix).
__global__ __launch_bounds__(128) void k_pool(const float* __restrict__ H,
                                              const int* __restrict__ gstart,
                                              float* __restrict__ psum){
  int g = blockIdx.x >> 6, slice = blockIdx.x & (PSL-1), t = threadIdx.x;
  int s0 = gstart[g], s1 = gstart[g+1];
  int cntg = s1 - s0;
  int chunk = (cntg + PSL-1) / PSL;
  int lo = s0 + slice*chunk;
  int hi = min(lo + chunk, s1);
  if (lo >= hi) return;
  float sum = 0.f;
  for (int i = lo; i < hi; i++) sum += H[(size_t)i*128 + t];
  atomicAdd(&psum[g*128 + t], sum);
}

__global__ __launch_bounds__(128) void k_mlp(const float* __restrict__ psum,
                       const int* __restrict__ gstart,
                       const float* __restrict__ w1, const float* __restrict__ b1,
                       const float* __restrict__ w2, const float* __restrict__ b2,
                       float* __restrict__ out)
{
  __shared__ float p[128];
  __shared__ float gsh[128];
  __shared__ float lg[10];
  int g = blockIdx.x, t = threadIdx.x;
  float c = fmaxf((float)(gstart[g+1] - gstart[g]), 1.f);
  p[t] = psum[g*128 + t] / c;
  __syncthreads();
  float acc = b1[t];
  for (int k = 0; k < 128; k++) acc = fmaf(p[k], w1[k*128 + t], acc);
  gsh[t] = acc > 0.f ? acc : 0.f;
  __syncthreads();
  if (t < 10){
    float a = b2[t];
    for (int k = 0; k < 128; k++) a = fmaf(gsh[k], w2[k*10 + t], a);
    lg[t] = a;
  }
  __syncthreads();
  if (t < 10){
    float mx = lg[0];
    for (int c2 = 1; c2 < 10; c2++) mx = fmaxf(mx, lg[c2]);
    float se = 0.f;
    for (int c2 = 0; c2 < 10; c2++) se += __expf(lg[c2] - mx);
    out[g*10 + t] = lg[t] - mx - logf(se);
  }
}

extern "C" void kernel_launch(void* const* d_in, const int* in_sizes, int n_in,
                              void* d_out, int out_size, void* d_ws, size_t ws_size,
                              hipStream_t stream)
{
  const float* x    = (const float*)d_in[0];
  const int* eidx   = (const int*)d_in[1];
  const int* batch  = (const int*)d_in[2];
  const float* W[3]  = {(const float*)d_in[3], (const float*)d_in[7],  (const float*)d_in[11]};
  const float* al[3] = {(const float*)d_in[4], (const float*)d_in[8],  (const float*)d_in[12]};
  const float* ar[3] = {(const float*)d_in[5], (const float*)d_in[9],  (const float*)d_in[13]};
  const float* bs[3] = {(const float*)d_in[6], (const float*)d_in[10], (const float*)d_in[14]};
  const float* l1w = (const float*)d_in[15];
  const float* l1b = (const float*)d_in[16];
  const float* l2w = (const float*)d_in[17];
  const float* l2b = (const float*)d_in[18];
  int E = in_sizes[1] / 2;
  int n = in_sizes[2];            // 100000
  const int* srcp = eidx;
  const int* dstp = eidx + E;
  int NB = (n + 255) >> SH;       // 391 buckets (<=512)

  char* wsp = (char*)d_ws;
  auto alloc = [&](size_t bytes){ void* p = (void*)wsp; wsp += (bytes + 255) & ~(size_t)255; return p; };
  unsigned short* xw   = (unsigned short*)alloc((size_t)n*128*2);  // 25.6 MB bf16
  unsigned short* hbuf = (unsigned short*)alloc((size_t)n*128*2);  // 25.6 MB bf16
  float* ALb  = (float*)alloc((size_t)n*4*4);
  float* ARb  = (float*)alloc((size_t)n*4*4);
  int* rp     = (int*)alloc((size_t)(n+1)*4);
  int* col    = (int*)alloc((size_t)E*4);          // 6.4 MB
  int2* tmp   = (int2*)alloc((size_t)E*8);         // 12.8 MB bucketed pairs
  int* bcnt   = (int*)alloc(512*4);
  int* bstart = (int*)alloc(513*4);
  int* bfill  = (int*)alloc(512*4);
  float* psum = (float*)alloc(64*128*4);
  int* gstart = (int*)alloc(65*4);
  unsigned short* wt3 = (unsigned short*)alloc(3*16384*2);   // W^T bf16 x3

  float* outlog = (float*)d_out;
  float* h3     = (float*)d_out + 64*10;

  int nparts = (E + TILE - 1) / TILE;   // 391

  k_init<<<193, 256, 0, stream>>>(bcnt, psum, W[0], W[1], W[2], wt3);
  // fused: bucket histogram + layer-1 GEMM (independent, co-resident)
  k_fuse1<<<nparts + 1024, 256, 0, stream>>>(dstp, bcnt, E, nparts,
                                             x, wt3, al[0], ar[0], xw, ALb, ARb, n);
  k_bscan<<<2, 256, 0, stream>>>(bcnt, bstart, bfill, NB, E, batch, gstart, n);
  k_part <<<nparts, 256, 0, stream>>>(srcp, dstp, bfill, tmp, E);
  k_csr  <<<NB, 256, 0, stream>>>(tmp, bstart, rp, col, n, E);

  int ablk = (n + 15) / 16;
  // layer 1 attention (xw ready from fuse1)
  k_attn<true><<<ablk, 256, 0, stream>>>(xw, ALb, ARb, rp, col, bs[0], hbuf, 0, n);
  // layer 2
  k_gemm<true><<<1024, 256, 0, stream>>>(hbuf, wt3 + 16384, al[1], ar[1], xw, ALb, ARb, n);
  k_attn<true><<<ablk, 256, 0, stream>>>(xw, ALb, ARb, rp, col, bs[1], hbuf, 0, n);
  // layer 3 -> fp32 straight into d_out
  k_gemm<true><<<1024, 256, 0, stream>>>(hbuf, wt3 + 32768, al[2], ar[2], xw, ALb, ARb, n);
  k_attn<false><<<ablk, 256, 0, stream>>>(xw, ALb, ARb, rp, col, bs[2], h3, 0, n);

  k_pool<<<64*PSL, 128, 0, stream>>>(h3, gstart, psum);
  k_mlp <<<64, 128, 0, stream>>>(psum, gstart, l1w, l1b, l2w, l2b, outlog);
}

// Round 9
// 492.253 us; speedup vs baseline: 1.1892x; 1.0151x over previous
//
#include <hip/hip_runtime.h>
#include <math.h>

// GAT 3-layer, MI355X. Round 15:
// Work-fusion extended: layer-1 GEMM tiles split across THREE launches --
// fuse1 [0,T1) + k_part2 [T1,T2) + k_csr2 [T2,ntiles). part/csr only launch
// 391 blocks (~1.5/CU, >70% machine idle); independent gemm1 tiles fill the
// idle CUs via extra blocks with manually-aliased LDS (char array union).
// attn/gemm2/gemm3/pool/mlp unchanged from R14.

#define LRELU(x) ((x) > 0.f ? (x) : 0.2f*(x))
#define SH 8          // bucket = dst >> 8 (256 nodes per bucket)
#define TILE 4096
#define EPT 16
#define PSL 64        // pool slices per graph

typedef __attribute__((ext_vector_type(8))) short s16x8;
typedef __attribute__((ext_vector_type(4))) float f32x4;

__device__ inline unsigned short f2bf(float f){
  unsigned u = __float_as_uint(f);
  u += 0x7fff + ((u >> 16) & 1);   // round-to-nearest-even
  return (unsigned short)(u >> 16);
}

// ---------------- init: zero bcnt + psum; transpose W1..W3 -> bf16 ------
__global__ void k_init(int* __restrict__ bcnt, float* __restrict__ psum,
                       const float* __restrict__ W0, const float* __restrict__ W1,
                       const float* __restrict__ W2, unsigned short* __restrict__ wt3){
  int t = threadIdx.x;
  if (blockIdx.x == 0){
    bcnt[t] = 0; bcnt[256 + t] = 0;
    for (int i = t; i < 8192; i += 256) psum[i] = 0.f;
    return;
  }
  int e = ((int)blockIdx.x - 1)*256 + t;   // 0..49151
  int layer = e >> 14, rem = e & 16383;
  int k = rem >> 7, nn = rem & 127;
  const float* Ws = layer == 0 ? W0 : (layer == 1 ? W1 : W2);
  wt3[layer*16384 + nn*128 + k] = f2bf(Ws[k*128 + nn]);
}

// ---------------- MFMA bf16 GEMM body (shared by all carriers) ----------
// Block 256 (4 waves). Tile 64 rows x 128 cols, K=128. Wave w owns cols
// [32w, 32w+32). B-fragments hoisted to registers from global W^T bf16.
// Iterates tiles in [tlo, thi) with grid-stride.
template<bool BF16IN>
__device__ __forceinline__ void gemm_body(
    unsigned short* Xl, unsigned short* Cl,
    const void* __restrict__ Xv, const unsigned short* __restrict__ Wtg,
    const float* __restrict__ attl, const float* __restrict__ attr,
    unsigned short* __restrict__ XW, float* __restrict__ AL, float* __restrict__ AR,
    int n, int tlo, int thi, int bid, int gstride)
{
  int t = threadIdx.x;
  int lane = t & 63, w = t >> 6;
  int l15 = lane & 15, quad = lane >> 4;
  int r_ = t >> 2, seg = t & 3;
  const unsigned short* Bp0 = Wtg + (w*32 + l15)*128 + quad*8;
  const unsigned short* Bp1 = Bp0 + 16*128;
  // hoist B fragments: loop-invariant, 8 x s16x8 = 32 VGPRs
  s16x8 b0r[4], b1r[4];
  #pragma unroll
  for (int ks = 0; ks < 4; ks++){
    b0r[ks] = *(const s16x8*)(Bp0 + ks*32);
    b1r[ks] = *(const s16x8*)(Bp1 + ks*32);
  }
  for (int tile = tlo + bid; tile < thi; tile += gstride){
    int row0 = tile << 6;
    {  // stage X tile as bf16
      int grow = row0 + r_;
      unsigned short* dp = &Xl[r_*136 + seg*32];
      if (grow < n){
        if (BF16IN){
          const uint4* gp = (const uint4*)((const unsigned short*)Xv + (size_t)grow*128 + seg*32);
          #pragma unroll
          for (int i = 0; i < 4; i++) ((uint4*)dp)[i] = gp[i];
        } else {
          const float4* gp = (const float4*)((const float*)Xv + (size_t)grow*128 + seg*32);
          #pragma unroll
          for (int i = 0; i < 8; i++){
            float4 v = gp[i];
            ((unsigned*)dp)[i*2]   = (unsigned)f2bf(v.x) | ((unsigned)f2bf(v.y) << 16);
            ((unsigned*)dp)[i*2+1] = (unsigned)f2bf(v.z) | ((unsigned)f2bf(v.w) << 16);
          }
        }
      } else {
        #pragma unroll
        for (int i = 0; i < 4; i++) ((uint4*)dp)[i] = make_uint4(0,0,0,0);
      }
    }
    __syncthreads();   // X visible; prev-tile Cl fully read
    f32x4 acc[4][2];
    #pragma unroll
    for (int rt = 0; rt < 4; rt++){ acc[rt][0] = (f32x4){0,0,0,0}; acc[rt][1] = (f32x4){0,0,0,0}; }
    #pragma unroll
    for (int ks = 0; ks < 4; ks++){
      #pragma unroll
      for (int rt = 0; rt < 4; rt++){
        s16x8 a = *(const s16x8*)&Xl[(rt*16 + l15)*136 + ks*32 + quad*8];
        acc[rt][0] = __builtin_amdgcn_mfma_f32_16x16x32_bf16(a, b0r[ks], acc[rt][0], 0, 0, 0);
        acc[rt][1] = __builtin_amdgcn_mfma_f32_16x16x32_bf16(a, b1r[ks], acc[rt][1], 0, 0, 0);
      }
    }
    // C layout: col = l15, row = quad*4 + reg -> separate Cl buffer (no bar)
    #pragma unroll
    for (int rt = 0; rt < 4; rt++)
      #pragma unroll
      for (int c2 = 0; c2 < 2; c2++)
        #pragma unroll
        for (int r = 0; r < 4; r++)
          Cl[(rt*16 + quad*4 + r)*136 + w*32 + c2*16 + l15] = f2bf(acc[rt][c2][r]);
    __syncthreads();   // C visible; X fully consumed
    {  // epilogue: thread -> (row r_, head seg)
      int grow = row0 + r_;
      if (grow < n){
        const unsigned short* sp = &Cl[r_*136 + seg*32];
        uint4 uu[4];
        #pragma unroll
        for (int i = 0; i < 4; i++) uu[i] = ((const uint4*)sp)[i];
        unsigned short* gx = XW + (size_t)grow*128 + seg*32;
        #pragma unroll
        for (int i = 0; i < 4; i++) ((uint4*)gx)[i] = uu[i];
        const unsigned* up = (const unsigned*)uu;
        const float4* alp = (const float4*)(attl + seg*32);
        const float4* arp = (const float4*)(attr + seg*32);
        float pl = 0.f, pr = 0.f;
        #pragma unroll
        for (int i = 0; i < 8; i++){
          unsigned ua = up[i*2], ub = up[i*2+1];
          float x0 = __uint_as_float(ua << 16);
          float x1 = __uint_as_float(ua & 0xffff0000u);
          float x2 = __uint_as_float(ub << 16);
          float x3 = __uint_as_float(ub & 0xffff0000u);
          float4 av = alp[i];
          float4 rv = arp[i];
          pl += x0*av.x + x1*av.y + x2*av.z + x3*av.w;
          pr += x0*rv.x + x1*rv.y + x2*rv.z + x3*rv.w;
        }
        AL[grow*4 + seg] = pl;
        AR[grow*4 + seg] = pr;
      }
    }
  }
}

template<bool BF16IN>
__global__ __launch_bounds__(256) void k_gemm(
    const void* __restrict__ Xv, const unsigned short* __restrict__ Wtg,
    const float* __restrict__ attl, const float* __restrict__ attr,
    unsigned short* __restrict__ XW, float* __restrict__ AL, float* __restrict__ AR, int n)
{
  __shared__ unsigned short Xl[64*136];
  __shared__ unsigned short Cl[64*136];
  int ntiles = (n + 63) >> 6;
  gemm_body<BF16IN>(Xl, Cl, Xv, Wtg, attl, attr, XW, AL, AR, n,
                    0, ntiles, blockIdx.x, gridDim.x);
}

// ---------------- fused: bucket histogram + GEMM-1 tiles [0,T1) --------
__global__ __launch_bounds__(256) void k_fuse1(
    const int* __restrict__ dst, int* __restrict__ bcnt, int E, int nparts,
    const float* __restrict__ X, const unsigned short* __restrict__ Wtg,
    const float* __restrict__ attl, const float* __restrict__ attr,
    unsigned short* __restrict__ XW, float* __restrict__ AL, float* __restrict__ AR,
    int n, int T1)
{
  __shared__ unsigned short Xl[64*136];
  __shared__ unsigned short Cl[64*136];
  if ((int)blockIdx.x < nparts){
    int* lh = (int*)Xl;     // alias histogram onto Xl
    int t = threadIdx.x;
    for (int j = t; j < 512; j += 256) lh[j] = 0;
    __syncthreads();
    int base = blockIdx.x * TILE;
    int lim = min(base + TILE, E);
    for (int e = base + t; e < lim; e += 256)
      atomicAdd(&lh[dst[e] >> SH], 1);
    __syncthreads();
    for (int j = t; j < 512; j += 256){
      int v = lh[j];
      if (v) atomicAdd(&bcnt[j], v);
    }
    return;
  }
  gemm_body<false>(Xl, Cl, X, Wtg, attl, attr, XW, AL, AR, n,
                   0, T1, (int)blockIdx.x - nparts, (int)gridDim.x - nparts);
}

// ---------------- bucket scan (block 0) + graph bounds (block 1) --------
__global__ __launch_bounds__(256) void k_bscan(const int* __restrict__ bcnt,
    int* __restrict__ bstart, int* __restrict__ bfill, int NB, int E,
    const int* __restrict__ batch, int* __restrict__ gstart, int n){
  int t = threadIdx.x;
  if (blockIdx.x == 1){
    int g = t;
    if (g > 64) return;
    int lo = 0, hi = n;
    while (lo < hi){
      int mid = (lo + hi) >> 1;
      if (batch[mid] < g) lo = mid + 1; else hi = mid;
    }
    gstart[g] = lo;
    return;
  }
  __shared__ int c[512];
  __shared__ int ps[256];
  for (int j = t; j < 512; j += 256) c[j] = (j < NB) ? bcnt[j] : 0;
  __syncthreads();
  int b0 = 2*t;
  int v0 = c[b0], v1 = c[b0+1];
  int ts = v0 + v1;
  ps[t] = ts; __syncthreads();
  for (int off = 1; off < 256; off <<= 1){
    int x = (t >= off) ? ps[t-off] : 0; __syncthreads();
    ps[t] += x; __syncthreads();
  }
  int pre = ps[t] - ts;
  if (b0   < NB){ bstart[b0]   = pre;    bfill[b0]   = pre; }
  if (b0+1 < NB){ bstart[b0+1] = pre+v0; bfill[b0+1] = pre+v0; }
  if (t == 0) bstart[NB] = E;
}

// ---------- LDS multi-split (blocks < nparts) + GEMM-1 tiles [T1,T2) ----
__global__ __launch_bounds__(256) void k_part2(const int* __restrict__ src,
    const int* __restrict__ dst, int* __restrict__ bfill,
    int2* __restrict__ tmp, int E,
    const float* __restrict__ X, const unsigned short* __restrict__ Wtg,
    const float* __restrict__ attl, const float* __restrict__ attr,
    unsigned short* __restrict__ XW, float* __restrict__ AL, float* __restrict__ AR,
    int n, int T1, int T2){
  __shared__ __align__(16) char smem[40960];
  int nparts = (E + TILE - 1) / TILE;
  int t = threadIdx.x;
  if ((int)blockIdx.x >= nparts){
    unsigned short* Xl = (unsigned short*)smem;
    unsigned short* Cl = (unsigned short*)(smem + 17408);
    gemm_body<false>(Xl, Cl, X, Wtg, attl, attr, XW, AL, AR, n,
                     T1, T2, (int)blockIdx.x - nparts, (int)gridDim.x - nparts);
    return;
  }
  int2* reorder = (int2*)smem;              // 32768
  int* lhist  = (int*)(smem + 32768);       // 2048
  int* lscan  = (int*)(smem + 34816);       // 2048
  int* lgbase = (int*)(smem + 36864);       // 2048
  int* ps     = (int*)(smem + 38912);       // 1024
  int tb = blockIdx.x * TILE;
  int tilecnt = min(TILE, E - tb);
  for (int j = t; j < 512; j += 256) lhist[j] = 0;
  __syncthreads();
  int ss[EPT], dd[EPT], rk[EPT];
  #pragma unroll
  for (int i = 0; i < EPT; i++){
    int e = tb + t + i*256;
    if (e < E){
      ss[i] = src[e]; dd[i] = dst[e];
      rk[i] = atomicAdd(&lhist[dd[i] >> SH], 1);
    }
  }
  __syncthreads();
  int b0 = 2*t;
  int v0 = lhist[b0], v1 = lhist[b0+1];
  int ts = v0 + v1;
  ps[t] = ts; __syncthreads();
  for (int off = 1; off < 256; off <<= 1){
    int x = (t >= off) ? ps[t-off] : 0; __syncthreads();
    ps[t] += x; __syncthreads();
  }
  int pre = ps[t] - ts;
  int ex0 = pre, ex1 = pre + v0;
  lscan[b0] = ex0; lscan[b0+1] = ex1;
  if (v0 > 0){ int gb = atomicAdd(&bfill[b0],   v0); lgbase[b0]   = gb - ex0; }
  if (v1 > 0){ int gb = atomicAdd(&bfill[b0+1], v1); lgbase[b0+1] = gb - ex1; }
  __syncthreads();
  #pragma unroll
  for (int i = 0; i < EPT; i++){
    int e = tb + t + i*256;
    if (e < E){
      int b = dd[i] >> SH;
      reorder[lscan[b] + rk[i]] = make_int2(ss[i], dd[i]);
    }
  }
  __syncthreads();
  for (int j = t; j < tilecnt; j += 256){
    int2 p = reorder[j];
    tmp[lgbase[p.y >> SH] + j] = p;
  }
}

// -------- CSR build (blocks < NB) + GEMM-1 tiles [T2, ntiles) -----------
__global__ __launch_bounds__(256) void k_csr2(const int2* __restrict__ tmp,
    const int* __restrict__ bstart, int* __restrict__ rp, int* __restrict__ col,
    int n, int E,
    const float* __restrict__ X, const unsigned short* __restrict__ Wtg,
    const float* __restrict__ attl, const float* __restrict__ attr,
    unsigned short* __restrict__ XW, float* __restrict__ AL, float* __restrict__ AR,
    int T2){
  __shared__ __align__(16) char smem[34816];
  int NB = (n + 255) >> SH;
  int t = threadIdx.x;
  if ((int)blockIdx.x >= NB){
    unsigned short* Xl = (unsigned short*)smem;
    unsigned short* Cl = (unsigned short*)(smem + 17408);
    int ntiles = (n + 63) >> 6;
    gemm_body<false>(Xl, Cl, X, Wtg, attl, attr, XW, AL, AR, n,
                     T2, ntiles, (int)blockIdx.x - NB, (int)gridDim.x - NB);
    return;
  }
  int* lcnt = (int*)smem;
  int* sc   = (int*)(smem + 1024);
  int b = blockIdx.x;
  int node0 = b << SH;
  int ncnt = min(256, n - node0);
  int be = bstart[b], ee = bstart[b+1];
  lcnt[t] = 0;
  __syncthreads();
  for (int e = be + t; e < ee; e += 256)
    atomicAdd(&lcnt[tmp[e].y - node0], 1);
  __syncthreads();
  int v = lcnt[t];
  sc[t] = v;
  __syncthreads();
  for (int off = 1; off < 256; off <<= 1){
    int x = (t >= off) ? sc[t-off] : 0;
    __syncthreads();
    sc[t] += x;
    __syncthreads();
  }
  int start = be + sc[t] - v;     // exclusive
  lcnt[t] = start;
  if (t < ncnt) rp[node0 + t] = start;
  if (t == 0 && node0 + ncnt == n) rp[n] = E;
  __syncthreads();
  for (int e = be + t; e < ee; e += 256){
    int2 p = tmp[e];
    int pos = atomicAdd(&lcnt[p.y - node0], 1);
    col[pos] = p.x;
  }
}

// ---------------- Attention + aggregate: 4 dsts per wave ----------------
// 16-lane group g owns dst d0+g; lane r owns channels 8r..8r+7.
// Phase 1 (wave-wide): weights for the union edge range packed into LDS as
// int2 {src<<4, w_h}. Phase 2 (per group): per-lane accumulation, no
// cross-lane reductions.
template<bool BF16OUT>
__global__ __launch_bounds__(256) void k_attn(
    const unsigned short* __restrict__ XW, const float* __restrict__ AL, const float* __restrict__ AR,
    const int* __restrict__ rp, const int* __restrict__ col,
    const float* __restrict__ bias, void* __restrict__ OUT, int dbase, int nmax)
{
  __shared__ int   ws[4][512];       // per wave: 64 edges x 4 heads x {s<<4, w}
  __shared__ float arsh[4][4][4];    // per wave: 4 dsts' ar (4 heads)
  int wv = threadIdx.x >> 6;
  int lane = threadIdx.x & 63;
  int r = lane & 15, g = lane >> 4, h2 = r >> 2;
  int d0 = dbase + (blockIdx.x*4 + wv)*4;
  if (d0 >= nmax) return;
  int d = d0 + g;
  bool valid = d < nmax;
  int dc = valid ? d : nmax-1;
  int rs = rp[dc];
  int re = valid ? rp[dc+1] : rs;
  float4 ard4 = ((const float4*)AR)[dc];
  if (r == 0) *(float4*)&arsh[wv][g][0] = ard4;
  float4 ald4 = ((const float4*)AL)[dc];
  float alh = h2==0?ald4.x : h2==1?ald4.y : h2==2?ald4.z : ald4.w;
  float arh = h2==0?ard4.x : h2==1?ard4.y : h2==2?ard4.z : ard4.w;
  float tse = alh + arh;
  float eself = __expf(fmaxf(tse, 0.2f*tse));
  const uint4* XW4 = (const uint4*)XW;
  float acc[8];
  {  // self term
    uint4 v = XW4[(size_t)dc*16 + r];
    acc[0] = eself * __uint_as_float(v.x << 16);
    acc[1] = eself * __uint_as_float(v.x & 0xffff0000u);
    acc[2] = eself * __uint_as_float(v.y << 16);
    acc[3] = eself * __uint_as_float(v.y & 0xffff0000u);
    acc[4] = eself * __uint_as_float(v.z << 16);
    acc[5] = eself * __uint_as_float(v.z & 0xffff0000u);
    acc[6] = eself * __uint_as_float(v.w << 16);
    acc[7] = eself * __uint_as_float(v.w & 0xffff0000u);
  }
  int ub0 = rp[d0];
  int ubE = rp[min(d0+4, nmax)];
  int reb = valid ? re : 0x7fffffff;
  int b1 = __shfl(reb, 0, 64);
  int b2 = __shfl(reb, 16, 64);
  int b3 = __shfl(reb, 32, 64);
  int* wsw = ws[wv];
  float zacc = eself;
  for (int cb = ub0; cb < ubE; cb += 64){
    int cnt = min(64, ubE - cb);
    if (lane < cnt){
      int e = cb + lane;
      int s = col[e];
      int eg = (e >= b1) + (e >= b2) + (e >= b3);
      float4 arr = *(const float4*)&arsh[wv][eg][0];
      float4 a = ((const float4*)AL)[s];
      float t0 = a.x + arr.x, t1 = a.y + arr.y, t2 = a.z + arr.z, t3 = a.w + arr.w;
      float w0 = __expf(fmaxf(t0, 0.2f*t0));
      float w1 = __expf(fmaxf(t1, 0.2f*t1));
      float w2 = __expf(fmaxf(t2, 0.2f*t2));
      float w3 = __expf(fmaxf(t3, 0.2f*t3));
      int s4 = s << 4;
      ((int4*)&wsw[lane*8])[0] = make_int4(s4, __float_as_int(w0), s4, __float_as_int(w1));
      ((int4*)&wsw[lane*8])[1] = make_int4(s4, __float_as_int(w2), s4, __float_as_int(w3));
    }
    int jlo = max(rs - cb, 0);
    int jhi = min(re - cb, cnt);
    #pragma unroll 4
    for (int j = jlo; j < jhi; ++j){
      int2 q = *(const int2*)&wsw[j*8 + h2*2];
      float w = __int_as_float(q.y);
      uint4 u = XW4[(unsigned)(q.x + r)];
      acc[0] = fmaf(w, __uint_as_float(u.x << 16), acc[0]);
      acc[1] = fmaf(w, __uint_as_float(u.x & 0xffff0000u), acc[1]);
      acc[2] = fmaf(w, __uint_as_float(u.y << 16), acc[2]);
      acc[3] = fmaf(w, __uint_as_float(u.y & 0xffff0000u), acc[3]);
      acc[4] = fmaf(w, __uint_as_float(u.z << 16), acc[4]);
      acc[5] = fmaf(w, __uint_as_float(u.z & 0xffff0000u), acc[5]);
      acc[6] = fmaf(w, __uint_as_float(u.w << 16), acc[6]);
      acc[7] = fmaf(w, __uint_as_float(u.w & 0xffff0000u), acc[7]);
      zacc += w;
    }
  }
  float rz = 1.f / zacc;
  float4 bb0 = ((const float4*)bias)[r*2];
  float4 bb1 = ((const float4*)bias)[r*2 + 1];
  float o[8];
  o[0] = fmaf(acc[0], rz, bb0.x); o[1] = fmaf(acc[1], rz, bb0.y);
  o[2] = fmaf(acc[2], rz, bb0.z); o[3] = fmaf(acc[3], rz, bb0.w);
  o[4] = fmaf(acc[4], rz, bb1.x); o[5] = fmaf(acc[5], rz, bb1.y);
  o[6] = fmaf(acc[6], rz, bb1.z); o[7] = fmaf(acc[7], rz, bb1.w);
  #pragma unroll
  for (int i = 0; i < 8; i++) o[i] = o[i] > 0.f ? o[i] : 0.f;
  if (valid){
    if (BF16OUT){
      uint4 pk;
      pk.x = (unsigned)f2bf(o[0]) | ((unsigned)f2bf(o[1]) << 16);
      pk.y = (unsigned)f2bf(o[2]) | ((unsigned)f2bf(o[3]) << 16);
      pk.z = (unsigned)f2bf(o[4]) | ((unsigned)f2bf(o[5]) << 16);
      pk.w = (unsigned)f2bf(o[6]) | ((unsigned)f2bf(o[7]) << 16);
      ((uint4*)OUT)[(size_t)d*16 + r] = pk;
    } else {
      float4 f0; f0.x = o[0]; f0.y = o[1]; f0.z = o[2]; f0.w = o[3];
      float4 f1; f1.x = o[4]; f1.y = o[5]; f1.z = o[6]; f1.w = o[7];
      ((float4*)OUT)[(size_t)d*32 + r*2]     = f0;
      ((float4*)OUT)[(size_t)d*32 + r*2 + 1] = f1;
    }
  }
}

// ---------------- pooling + MLP head ----------------
// 64 slices/graph (4096 blocks): ~24 rows/block, BW-bound (R12 fix).
__global__ __launch_bounds__(128) void k_pool(const float* __restrict__ H,
                                              const int* __restrict__ gstart,
                                              float* __restrict__ psum){
  int g = blockIdx.x >> 6, slice = blockIdx.x & (PSL-1), t = threadIdx.x;
  int s0 = gstart[g], s1 = gstart[g+1];
  int cntg = s1 - s0;
  int chunk = (cntg + PSL-1) / PSL;
  int lo = s0 + slice*chunk;
  int hi = min(lo + chunk, s1);
  if (lo >= hi) return;
  float sum = 0.f;
  for (int i = lo; i < hi; i++) sum += H[(size_t)i*128 + t];
  atomicAdd(&psum[g*128 + t], sum);
}

__global__ __launch_bounds__(128) void k_mlp(const float* __restrict__ psum,
                       const int* __restrict__ gstart,
                       const float* __restrict__ w1, const float* __restrict__ b1,
                       const float* __restrict__ w2, const float* __restrict__ b2,
                       float* __restrict__ out)
{
  __shared__ float p[128];
  __shared__ float gsh[128];
  __shared__ float lg[10];
  int g = blockIdx.x, t = threadIdx.x;
  float c = fmaxf((float)(gstart[g+1] - gstart[g]), 1.f);
  p[t] = psum[g*128 + t] / c;
  __syncthreads();
  float acc = b1[t];
  for (int k = 0; k < 128; k++) acc = fmaf(p[k], w1[k*128 + t], acc);
  gsh[t] = acc > 0.f ? acc : 0.f;
  __syncthreads();
  if (t < 10){
    float a = b2[t];
    for (int k = 0; k < 128; k++) a = fmaf(gsh[k], w2[k*10 + t], a);
    lg[t] = a;
  }
  __syncthreads();
  if (t < 10){
    float mx = lg[0];
    for (int c2 = 1; c2 < 10; c2++) mx = fmaxf(mx, lg[c2]);
    float se = 0.f;
    for (int c2 = 0; c2 < 10; c2++) se += __expf(lg[c2] - mx);
    out[g*10 + t] = lg[t] - mx - logf(se);
  }
}

extern "C" void kernel_launch(void* const* d_in, const int* in_sizes, int n_in,
                              void* d_out, int out_size, void* d_ws, size_t ws_size,
                              hipStream_t stream)
{
  const float* x    = (const float*)d_in[0];
  const int* eidx   = (const int*)d_in[1];
  const int* batch  = (const int*)d_in[2];
  const float* W[3]  = {(const float*)d_in[3], (const float*)d_in[7],  (const float*)d_in[11]};
  const float* al[3] = {(const float*)d_in[4], (const float*)d_in[8],  (const float*)d_in[12]};
  const float* ar[3] = {(const float*)d_in[5], (const float*)d_in[9],  (const float*)d_in[13]};
  const float* bs[3] = {(const float*)d_in[6], (const float*)d_in[10], (const float*)d_in[14]};
  const float* l1w = (const float*)d_in[15];
  const float* l1b = (const float*)d_in[16];
  const float* l2w = (const float*)d_in[17];
  const float* l2b = (const float*)d_in[18];
  int E = in_sizes[1] / 2;
  int n = in_sizes[2];            // 100000
  const int* srcp = eidx;
  const int* dstp = eidx + E;
  int NB = (n + 255) >> SH;       // 391 buckets (<=512)

  char* wsp = (char*)d_ws;
  auto alloc = [&](size_t bytes){ void* p = (void*)wsp; wsp += (bytes + 255) & ~(size_t)255; return p; };
  unsigned short* xw   = (unsigned short*)alloc((size_t)n*128*2);  // 25.6 MB bf16
  unsigned short* hbuf = (unsigned short*)alloc((size_t)n*128*2);  // 25.6 MB bf16
  float* ALb  = (float*)alloc((size_t)n*4*4);
  float* ARb  = (float*)alloc((size_t)n*4*4);
  int* rp     = (int*)alloc((size_t)(n+1)*4);
  int* col    = (int*)alloc((size_t)E*4);          // 6.4 MB
  int2* tmp   = (int2*)alloc((size_t)E*8);         // 12.8 MB bucketed pairs
  int* bcnt   = (int*)alloc(512*4);
  int* bstart = (int*)alloc(513*4);
  int* bfill  = (int*)alloc(512*4);
  float* psum = (float*)alloc(64*128*4);
  int* gstart = (int*)alloc(65*4);
  unsigned short* wt3 = (unsigned short*)alloc(3*16384*2);   // W^T bf16 x3

  float* outlog = (float*)d_out;
  float* h3     = (float*)d_out + 64*10;

  int nparts = (E + TILE - 1) / TILE;   // 391
  int ntiles = (n + 63) >> 6;           // 1563
  // tile partition: fuse1 small head; bulk rides in part2/csr2's idle CUs
  int T1 = ntiles / 6;                                   // ~260
  int T2 = T1 + (int)((long long)(ntiles - T1) * 54 / 100);  // ~964
  int G1 = T1 > 0 ? T1 : 1;
  int G2 = (T2 - T1) > 0 ? (T2 - T1) : 1;
  int G3 = (ntiles - T2) > 0 ? (ntiles - T2) : 1;

  k_init<<<193, 256, 0, stream>>>(bcnt, psum, W[0], W[1], W[2], wt3);
  k_fuse1<<<nparts + G1, 256, 0, stream>>>(dstp, bcnt, E, nparts,
                                           x, wt3, al[0], ar[0], xw, ALb, ARb, n, T1);
  k_bscan<<<2, 256, 0, stream>>>(bcnt, bstart, bfill, NB, E, batch, gstart, n);
  k_part2<<<nparts + G2, 256, 0, stream>>>(srcp, dstp, bfill, tmp, E,
                                           x, wt3, al[0], ar[0], xw, ALb, ARb, n, T1, T2);
  k_csr2 <<<NB + G3, 256, 0, stream>>>(tmp, bstart, rp, col, n, E,
                                       x, wt3, al[0], ar[0], xw, ALb, ARb, T2);

  int ablk = (n + 15) / 16;
  // layer 1 attention (xw complete after csr2)
  k_attn<true><<<ablk, 256, 0, stream>>>(xw, ALb, ARb, rp, col, bs[0], hbuf, 0, n);
  // layer 2
  k_gemm<true><<<1024, 256, 0, stream>>>(hbuf, wt3 + 16384, al[1], ar[1], xw, ALb, ARb, n);
  k_attn<true><<<ablk, 256, 0, stream>>>(xw, ALb, ARb, rp, col, bs[1], hbuf, 0, n);
  // layer 3 -> fp32 straight into d_out
  k_gemm<true><<<1024, 256, 0, stream>>>(hbuf, wt3 + 32768, al[2], ar[2], xw, ALb, ARb, n);
  k_attn<false><<<ablk, 256, 0, stream>>>(xw, ALb, ARb, rp, col, bs[2], h3, 0, n);

  k_pool<<<64*PSL, 128, 0, stream>>>(h3, gstart, psum);
  k_mlp <<<64, 128, 0, stream>>>(psum, gstart, l1w, l1b, l2w, l2b, outlog);
}